// Round 1
// baseline (974.970 us; speedup 1.0000x reference)
//
#include <hip/hip_runtime.h>

#define NN 100000
#define NE 1600000
#define CC 128
#define NB_SCAN 391   // ceil(NN/256)

// ---------------- degree / norm ----------------
__global__ void k_init(float* deg, int* cnt) {
    int i = blockIdx.x * 256 + threadIdx.x;
    if (i < NN) { deg[i] = 1.0f; cnt[i] = 0; }
}

__global__ void k_deg_count(const int* __restrict__ ei, const float* __restrict__ ew,
                            float* deg, int* cnt) {
    int e = blockIdx.x * 256 + threadIdx.x;
    if (e < NE) {
        int c = ei[NE + e];
        atomicAdd(&deg[c], ew[e]);
        atomicAdd(&cnt[c], 1);
    }
}

__global__ void k_dinv(const float* __restrict__ deg, float* dinv) {
    int i = blockIdx.x * 256 + threadIdx.x;
    if (i < NN) dinv[i] = rsqrtf(deg[i]);   // deg >= 1 always (self-loop)
}

// ---------------- prefix scan (counts -> rowptr) ----------------
__global__ void k_scan1(const int* __restrict__ cnt, int* rowptr, int* bsum) {
    __shared__ int s[256];
    int t = threadIdx.x;
    int i = blockIdx.x * 256 + t;
    int v = (i < NN) ? cnt[i] : 0;
    s[t] = v; __syncthreads();
    for (int off = 1; off < 256; off <<= 1) {
        int x = (t >= off) ? s[t - off] : 0;
        __syncthreads();
        s[t] += x;
        __syncthreads();
    }
    if (i < NN) rowptr[i] = s[t] - v;         // exclusive
    if (t == 255) bsum[blockIdx.x] = s[255];  // block total
}

__global__ void k_scan2(const int* __restrict__ bsum, int* boff) {
    __shared__ int s[512];
    int t = threadIdx.x;
    int v = (t < NB_SCAN) ? bsum[t] : 0;
    s[t] = v; __syncthreads();
    for (int off = 1; off < 512; off <<= 1) {
        int x = (t >= off) ? s[t - off] : 0;
        __syncthreads();
        s[t] += x;
        __syncthreads();
    }
    if (t < NB_SCAN) boff[t] = s[t] - v;      // exclusive
}

__global__ void k_scan3(int* rowptr, const int* __restrict__ boff, int* cursor) {
    int i = blockIdx.x * 256 + threadIdx.x;
    if (i < NN) {
        int r = rowptr[i] + boff[i >> 8];
        rowptr[i] = r;
        cursor[i] = r;
    }
    if (i == 0) rowptr[NN] = NE;
}

__global__ void k_fill(const int* __restrict__ ei, const float* __restrict__ ew,
                       int* cursor, int* csr_src, float* csr_w) {
    int e = blockIdx.x * 256 + threadIdx.x;
    if (e < NE) {
        int c = ei[NE + e];
        int pos = atomicAdd(&cursor[c], 1);
        csr_src[pos] = ei[e];
        csr_w[pos] = ew[e];
    }
}

// ---------------- embW0 = emb @ W0 (128x128x128, tiny) ----------------
__global__ void k_embw(const float* __restrict__ emb, const float* __restrict__ w0,
                       float* embw) {
    int t = blockIdx.x * 256 + threadIdx.x;  // 16384 threads
    int i = t >> 7, j = t & 127;
    float acc = 0.f;
    for (int k = 0; k < 128; k++) acc = fmaf(emb[i * 128 + k], w0[k * 128 + j], acc);
    embw[t] = acc;
}

// y1[v] = dinv[v] * embW0[x_idx[v]]
__global__ void k_gather(const int* __restrict__ xidx, const float* __restrict__ dinv,
                         const float* __restrict__ embw, float* y) {
    int t = blockIdx.x * 256 + threadIdx.x;  // NN*32 threads
    if (t < NN * 32) {
        int v = t >> 5, q = t & 31;
        float s = dinv[v];
        float4 e = reinterpret_cast<const float4*>(embw)[xidx[v] * 32 + q];
        float4 r; r.x = s * e.x; r.y = s * e.y; r.z = s * e.z; r.w = s * e.w;
        reinterpret_cast<float4*>(y)[t] = r;
    }
}

// ---------------- aggregation: xout[v] = relu?(dinv[v]*(sum_e w*y[src] + y[v]) + b)
__global__ void k_agg(const float* __restrict__ y, const int* __restrict__ rowptr,
                      const int* __restrict__ csr_src, const float* __restrict__ csr_w,
                      const float* __restrict__ dinv, const float* __restrict__ bias,
                      float* __restrict__ xout, int relu) {
    int wave = threadIdx.x >> 6;
    int lane = threadIdx.x & 63;
    int v = blockIdx.x * 4 + wave;
    if (v >= NN) return;
    int beg = rowptr[v], end = rowptr[v + 1];
    const float2* y2 = reinterpret_cast<const float2*>(y);
    float ax = 0.f, ay = 0.f;
    for (int e = beg; e < end; e++) {
        int src = csr_src[e];
        float wt = csr_w[e];
        float2 t = y2[src * 64 + lane];
        ax = fmaf(wt, t.x, ax);
        ay = fmaf(wt, t.y, ay);
    }
    float2 self = y2[v * 64 + lane];
    ax += self.x; ay += self.y;
    float s = dinv[v];
    float2 b = reinterpret_cast<const float2*>(bias)[lane];
    float ox = fmaf(s, ax, b.x);
    float oy = fmaf(s, ay, b.y);
    if (relu) { ox = fmaxf(ox, 0.f); oy = fmaxf(oy, 0.f); }
    float2 r; r.x = ox; r.y = oy;
    reinterpret_cast<float2*>(xout)[v * 64 + lane] = r;
}

// ---------------- GEMM: out[n][j] = epi( sum_k A[n][k] * W[k][j] ) ----------------
// MODE 0: out = dinv[n] * dot        MODE 1: out = relu(dot + bias[j])
template <int MODE>
__global__ __launch_bounds__(256) void k_gemm(const float* __restrict__ A,
                                              const float* __restrict__ W,
                                              const float* __restrict__ dinv,
                                              const float* __restrict__ bias,
                                              float* __restrict__ out) {
    __shared__ float As[32][68];    // [k][m], padded
    __shared__ float Bs[32][128];   // [k][j]
    int t = threadIdx.x;
    int tx = t & 15, ty = t >> 4;
    int m0 = blockIdx.x * 64;

    float acc[4][8];
#pragma unroll
    for (int i = 0; i < 4; i++)
#pragma unroll
        for (int j = 0; j < 8; j++) acc[i][j] = 0.f;

    for (int kk = 0; kk < 128; kk += 32) {
        // A tile: 64 rows x 32 k
        {
            int q = t & 7;   // float4 index along k
            int m = t >> 3;  // 0..31
#pragma unroll
            for (int p = 0; p < 2; p++) {
                int mm = m + p * 32;
                int row = m0 + mm;
                float4 a = (row < NN)
                               ? reinterpret_cast<const float4*>(&A[row * 128 + kk])[q]
                               : make_float4(0.f, 0.f, 0.f, 0.f);
                As[q * 4 + 0][mm] = a.x;
                As[q * 4 + 1][mm] = a.y;
                As[q * 4 + 2][mm] = a.z;
                As[q * 4 + 3][mm] = a.w;
            }
        }
        // B tile: 32 k x 128 j
        {
            int j4 = t & 31;
            int k = t >> 5;  // 0..7
#pragma unroll
            for (int p = 0; p < 4; p++) {
                int kr = k + p * 8;
                reinterpret_cast<float4*>(&Bs[kr][0])[j4] =
                    reinterpret_cast<const float4*>(&W[(kk + kr) * 128])[j4];
            }
        }
        __syncthreads();
#pragma unroll
        for (int k = 0; k < 32; k++) {
            const float4 a = *reinterpret_cast<const float4*>(&As[k][ty * 4]);
            const float4 p = *reinterpret_cast<const float4*>(&Bs[k][tx * 8]);
            const float4 q = *reinterpret_cast<const float4*>(&Bs[k][tx * 8 + 4]);
            float av[4] = {a.x, a.y, a.z, a.w};
            float bv[8] = {p.x, p.y, p.z, p.w, q.x, q.y, q.z, q.w};
#pragma unroll
            for (int i = 0; i < 4; i++)
#pragma unroll
                for (int j = 0; j < 8; j++) acc[i][j] = fmaf(av[i], bv[j], acc[i][j]);
        }
        __syncthreads();
    }

    float bv[8];
    if (MODE == 1) {
#pragma unroll
        for (int j = 0; j < 8; j++) bv[j] = bias[tx * 8 + j];
    }
#pragma unroll
    for (int i = 0; i < 4; i++) {
        int row = m0 + ty * 4 + i;
        if (row < NN) {
            float o[8];
            if (MODE == 0) {
                float s = dinv[row];
#pragma unroll
                for (int j = 0; j < 8; j++) o[j] = s * acc[i][j];
            } else {
#pragma unroll
                for (int j = 0; j < 8; j++) o[j] = fmaxf(acc[i][j] + bv[j], 0.f);
            }
            float4 o0 = make_float4(o[0], o[1], o[2], o[3]);
            float4 o1 = make_float4(o[4], o[5], o[6], o[7]);
            *reinterpret_cast<float4*>(&out[row * 128 + tx * 8]) = o0;
            *reinterpret_cast<float4*>(&out[row * 128 + tx * 8 + 4]) = o1;
        }
    }
}

// ---------------- lin2: out[v] = h[v] @ W2 + b2  (128 -> 2) ----------------
__global__ void k_lin2(const float* __restrict__ h, const float* __restrict__ w2,
                       const float* __restrict__ b2, float* __restrict__ out) {
    int wave = threadIdx.x >> 6, lane = threadIdx.x & 63;
    int v = blockIdx.x * 4 + wave;
    if (v >= NN) return;
    float h0 = h[v * 128 + lane], h1 = h[v * 128 + 64 + lane];
    float d0 = h0 * w2[lane * 2 + 0] + h1 * w2[(lane + 64) * 2 + 0];
    float d1 = h0 * w2[lane * 2 + 1] + h1 * w2[(lane + 64) * 2 + 1];
    for (int off = 32; off; off >>= 1) {
        d0 += __shfl_down(d0, off);
        d1 += __shfl_down(d1, off);
    }
    if (lane == 0) {
        out[v * 2 + 0] = d0 + b2[0];
        out[v * 2 + 1] = d1 + b2[1];
    }
}

extern "C" void kernel_launch(void* const* d_in, const int* in_sizes, int n_in,
                              void* d_out, int out_size, void* d_ws, size_t ws_size,
                              hipStream_t stream) {
    const int*   x_idx  = (const int*)d_in[0];
    const int*   ei     = (const int*)d_in[1];
    const float* ew     = (const float*)d_in[2];
    const float* emb    = (const float*)d_in[3];
    const float* conv_w = (const float*)d_in[4];
    const float* conv_b = (const float*)d_in[5];
    const float* lin1_w = (const float*)d_in[6];
    const float* lin1_b = (const float*)d_in[7];
    const float* lin2_w = (const float*)d_in[8];
    const float* lin2_b = (const float*)d_in[9];
    float* out = (float*)d_out;

    char* ws = (char*)d_ws;
    size_t off = 0;
    auto alloc = [&](size_t bytes) -> void* {
        void* p = ws + off;
        off += (bytes + 255) & ~(size_t)255;
        return p;
    };
    float* deg     = (float*)alloc(NN * 4);
    float* dinv    = (float*)alloc(NN * 4);
    int*   cnt     = (int*)alloc(NN * 4);
    int*   rowptr  = (int*)alloc((NN + 1) * 4);
    int*   cursor  = (int*)alloc(NN * 4);
    int*   bsum    = (int*)alloc(512 * 4);
    int*   boff    = (int*)alloc(512 * 4);
    int*   csr_src = (int*)alloc((size_t)NE * 4);
    float* csr_w   = (float*)alloc((size_t)NE * 4);
    float* embw    = (float*)alloc(128 * 128 * 4);
    float* bufA    = (float*)alloc((size_t)NN * CC * 4);
    float* bufB    = (float*)alloc((size_t)NN * CC * 4);
    (void)ws_size;

    const int NBn = (NN + 255) / 256;       // 391
    const int NBe = (NE + 255) / 256;       // 6250

    k_init<<<NBn, 256, 0, stream>>>(deg, cnt);
    k_deg_count<<<NBe, 256, 0, stream>>>(ei, ew, deg, cnt);
    k_dinv<<<NBn, 256, 0, stream>>>(deg, dinv);
    k_scan1<<<NB_SCAN, 256, 0, stream>>>(cnt, rowptr, bsum);
    k_scan2<<<1, 512, 0, stream>>>(bsum, boff);
    k_scan3<<<NBn, 256, 0, stream>>>(rowptr, boff, cursor);
    k_fill<<<NBe, 256, 0, stream>>>(ei, ew, cursor, csr_src, csr_w);

    // layer 0 GEMM collapses: embw = emb @ W0 ; y1 = dinv * embw[x_idx]
    k_embw<<<64, 256, 0, stream>>>(emb, conv_w, embw);
    k_gather<<<(NN * 32 + 255) / 256, 256, 0, stream>>>(x_idx, dinv, embw, bufA);

    // layer 0 aggregate -> x2 (relu)
    k_agg<<<NN / 4, 256, 0, stream>>>(bufA, rowptr, csr_src, csr_w, dinv,
                                      conv_b + 0 * CC, bufB, 1);
    // layer 1: y2 = dinv*(x2 @ W1)
    k_gemm<0><<<(NN + 63) / 64, 256, 0, stream>>>(bufB, conv_w + 1 * CC * CC, dinv,
                                                  nullptr, bufA);
    k_agg<<<NN / 4, 256, 0, stream>>>(bufA, rowptr, csr_src, csr_w, dinv,
                                      conv_b + 1 * CC, bufB, 1);
    // layer 2: y3 = dinv*(x3 @ W2)
    k_gemm<0><<<(NN + 63) / 64, 256, 0, stream>>>(bufB, conv_w + 2 * CC * CC, dinv,
                                                  nullptr, bufA);
    k_agg<<<NN / 4, 256, 0, stream>>>(bufA, rowptr, csr_src, csr_w, dinv,
                                      conv_b + 2 * CC, bufB, 0);
    // lin1: h = relu(x4 @ lin1_w + lin1_b)
    k_gemm<1><<<(NN + 63) / 64, 256, 0, stream>>>(bufB, lin1_w, nullptr, lin1_b, bufA);
    // lin2
    k_lin2<<<NN / 4, 256, 0, stream>>>(bufA, lin2_w, lin2_b, out);
}

// Round 2
// 748.150 us; speedup vs baseline: 1.3032x; 1.3032x over previous
//
#include <hip/hip_runtime.h>

#define NN 100000
#define NE 1600000
#define CC 128
#define NB_SCAN 391   // ceil(NN/256)

// ---------------- degree / norm ----------------
__global__ void k_init(float* deg, int* cnt) {
    int i = blockIdx.x * 256 + threadIdx.x;
    if (i < NN) { deg[i] = 1.0f; cnt[i] = 0; }
}

__global__ void k_deg_count(const int* __restrict__ ei, const float* __restrict__ ew,
                            float* deg, int* cnt) {
    int e = blockIdx.x * 256 + threadIdx.x;
    if (e < NE) {
        int c = ei[NE + e];
        atomicAdd(&deg[c], ew[e]);
        atomicAdd(&cnt[c], 1);
    }
}

__global__ void k_dinv(const float* __restrict__ deg, float* dinv) {
    int i = blockIdx.x * 256 + threadIdx.x;
    if (i < NN) dinv[i] = rsqrtf(deg[i]);   // deg >= 1 always (self-loop)
}

// ---------------- prefix scan (counts -> rowptr) ----------------
__global__ void k_scan1(const int* __restrict__ cnt, int* rowptr, int* bsum) {
    __shared__ int s[256];
    int t = threadIdx.x;
    int i = blockIdx.x * 256 + t;
    int v = (i < NN) ? cnt[i] : 0;
    s[t] = v; __syncthreads();
    for (int off = 1; off < 256; off <<= 1) {
        int x = (t >= off) ? s[t - off] : 0;
        __syncthreads();
        s[t] += x;
        __syncthreads();
    }
    if (i < NN) rowptr[i] = s[t] - v;         // exclusive
    if (t == 255) bsum[blockIdx.x] = s[255];  // block total
}

__global__ void k_scan2(const int* __restrict__ bsum, int* boff) {
    __shared__ int s[512];
    int t = threadIdx.x;
    int v = (t < NB_SCAN) ? bsum[t] : 0;
    s[t] = v; __syncthreads();
    for (int off = 1; off < 512; off <<= 1) {
        int x = (t >= off) ? s[t - off] : 0;
        __syncthreads();
        s[t] += x;
        __syncthreads();
    }
    if (t < NB_SCAN) boff[t] = s[t] - v;      // exclusive
}

__global__ void k_scan3(int* rowptr, const int* __restrict__ boff, int* cursor) {
    int i = blockIdx.x * 256 + threadIdx.x;
    if (i < NN) {
        int r = rowptr[i] + boff[i >> 8];
        rowptr[i] = r;
        cursor[i] = r;
    }
    if (i == 0) rowptr[NN] = NE;
}

// CSR fill. csr12 = {src, w} for layers 1-2.
// csr0 = {emb_row(src), w*dinv[src]} so layer-0 agg gathers from the 64KB
// L2-resident embW0 table instead of a 51MB y buffer.
__global__ void k_fill(const int* __restrict__ ei, const float* __restrict__ ew,
                       const int* __restrict__ xidx, const float* __restrict__ dinv,
                       int* cursor, int2* csr0, int2* csr12) {
    int e = blockIdx.x * 256 + threadIdx.x;
    if (e < NE) {
        int src = ei[e];
        int c = ei[NE + e];
        float w = ew[e];
        int pos = atomicAdd(&cursor[c], 1);
        csr12[pos] = make_int2(src, __float_as_int(w));
        csr0[pos] = make_int2(xidx[src], __float_as_int(w * dinv[src]));
    }
}

// ---------------- embW0 = emb @ W0 (128x128x128, tiny) ----------------
__global__ void k_embw(const float* __restrict__ emb, const float* __restrict__ w0,
                       float* embw) {
    int t = blockIdx.x * 256 + threadIdx.x;  // 16384 threads
    int i = t >> 7, j = t & 127;
    float acc = 0.f;
    for (int k = 0; k < 128; k++) acc = fmaf(emb[i * 128 + k], w0[k * 128 + j], acc);
    embw[t] = acc;
}

// ---------------- layer-0 aggregation, fused gather from embW0 ----------------
// xout[v] = relu(dinv[v]*(sum_e wsc_e*embw[row_e] + dinv[v]*embw[xidx[v]]) + b)
__global__ void k_agg0(const int2* __restrict__ csr0, const int* __restrict__ rowptr,
                       const int* __restrict__ xidx, const float* __restrict__ dinv,
                       const float* __restrict__ embw, const float* __restrict__ bias,
                       float* __restrict__ xout) {
    int wave = threadIdx.x >> 6, lane = threadIdx.x & 63;
    int v = blockIdx.x * 4 + wave;
    if (v >= NN) return;
    int beg = rowptr[v], end = rowptr[v + 1];
    const float2* e2 = reinterpret_cast<const float2*>(embw);
    float ax = 0.f, ay = 0.f;
    int e = beg;
    while (e + 8 <= end) {
        int2 c[8]; float2 t[8];
#pragma unroll
        for (int u = 0; u < 8; u++) c[u] = csr0[e + u];
#pragma unroll
        for (int u = 0; u < 8; u++) t[u] = e2[c[u].x * 64 + lane];
#pragma unroll
        for (int u = 0; u < 8; u++) {
            float w = __int_as_float(c[u].y);
            ax = fmaf(w, t[u].x, ax);
            ay = fmaf(w, t[u].y, ay);
        }
        e += 8;
    }
    if (e + 4 <= end) {
        int2 c[4]; float2 t[4];
#pragma unroll
        for (int u = 0; u < 4; u++) c[u] = csr0[e + u];
#pragma unroll
        for (int u = 0; u < 4; u++) t[u] = e2[c[u].x * 64 + lane];
#pragma unroll
        for (int u = 0; u < 4; u++) {
            float w = __int_as_float(c[u].y);
            ax = fmaf(w, t[u].x, ax);
            ay = fmaf(w, t[u].y, ay);
        }
        e += 4;
    }
    for (; e < end; ++e) {
        int2 c = csr0[e];
        float2 t = e2[c.x * 64 + lane];
        float w = __int_as_float(c.y);
        ax = fmaf(w, t.x, ax);
        ay = fmaf(w, t.y, ay);
    }
    float dv = dinv[v];
    float2 ts = e2[xidx[v] * 64 + lane];   // self loop: y[v] = dinv[v]*embw[xidx[v]]
    ax = fmaf(dv, ts.x, ax);
    ay = fmaf(dv, ts.y, ay);
    float2 b = reinterpret_cast<const float2*>(bias)[lane];
    float ox = fmaxf(fmaf(dv, ax, b.x), 0.f);
    float oy = fmaxf(fmaf(dv, ay, b.y), 0.f);
    reinterpret_cast<float2*>(xout)[v * 64 + lane] = make_float2(ox, oy);
}

// ---------------- aggregation: xout[v] = relu?(dinv[v]*(sum_e w*y[src] + y[v]) + b)
__global__ void k_agg(const float* __restrict__ y, const int* __restrict__ rowptr,
                      const int2* __restrict__ csr, const float* __restrict__ dinv,
                      const float* __restrict__ bias, float* __restrict__ xout,
                      int relu) {
    int wave = threadIdx.x >> 6, lane = threadIdx.x & 63;
    int v = blockIdx.x * 4 + wave;
    if (v >= NN) return;
    int beg = rowptr[v], end = rowptr[v + 1];
    const float2* y2 = reinterpret_cast<const float2*>(y);
    float ax = 0.f, ay = 0.f;
    int e = beg;
    while (e + 8 <= end) {
        int2 c[8]; float2 t[8];
#pragma unroll
        for (int u = 0; u < 8; u++) c[u] = csr[e + u];
#pragma unroll
        for (int u = 0; u < 8; u++) t[u] = y2[c[u].x * 64 + lane];
#pragma unroll
        for (int u = 0; u < 8; u++) {
            float w = __int_as_float(c[u].y);
            ax = fmaf(w, t[u].x, ax);
            ay = fmaf(w, t[u].y, ay);
        }
        e += 8;
    }
    if (e + 4 <= end) {
        int2 c[4]; float2 t[4];
#pragma unroll
        for (int u = 0; u < 4; u++) c[u] = csr[e + u];
#pragma unroll
        for (int u = 0; u < 4; u++) t[u] = y2[c[u].x * 64 + lane];
#pragma unroll
        for (int u = 0; u < 4; u++) {
            float w = __int_as_float(c[u].y);
            ax = fmaf(w, t[u].x, ax);
            ay = fmaf(w, t[u].y, ay);
        }
        e += 4;
    }
    for (; e < end; ++e) {
        int2 c = csr[e];
        float2 t = y2[c.x * 64 + lane];
        float w = __int_as_float(c.y);
        ax = fmaf(w, t.x, ax);
        ay = fmaf(w, t.y, ay);
    }
    float2 self = y2[v * 64 + lane];
    ax += self.x; ay += self.y;
    float s = dinv[v];
    float2 b = reinterpret_cast<const float2*>(bias)[lane];
    float ox = fmaf(s, ax, b.x);
    float oy = fmaf(s, ay, b.y);
    if (relu) { ox = fmaxf(ox, 0.f); oy = fmaxf(oy, 0.f); }
    reinterpret_cast<float2*>(xout)[v * 64 + lane] = make_float2(ox, oy);
}

// ---------------- GEMM: out[n][j] = epi( sum_k A[n][k] * W[k][j] ) ----------------
// MODE 0: out = dinv[n] * dot        MODE 1: out = relu(dot + bias[j])
template <int MODE>
__global__ __launch_bounds__(256) void k_gemm(const float* __restrict__ A,
                                              const float* __restrict__ W,
                                              const float* __restrict__ dinv,
                                              const float* __restrict__ bias,
                                              float* __restrict__ out) {
    __shared__ float As[32][68];    // [k][m], padded
    __shared__ float Bs[32][128];   // [k][j]
    int t = threadIdx.x;
    int tx = t & 15, ty = t >> 4;
    int m0 = blockIdx.x * 64;

    float acc[4][8];
#pragma unroll
    for (int i = 0; i < 4; i++)
#pragma unroll
        for (int j = 0; j < 8; j++) acc[i][j] = 0.f;

    for (int kk = 0; kk < 128; kk += 32) {
        {
            int q = t & 7;   // float4 index along k
            int m = t >> 3;  // 0..31
#pragma unroll
            for (int p = 0; p < 2; p++) {
                int mm = m + p * 32;
                int row = m0 + mm;
                float4 a = (row < NN)
                               ? reinterpret_cast<const float4*>(&A[row * 128 + kk])[q]
                               : make_float4(0.f, 0.f, 0.f, 0.f);
                As[q * 4 + 0][mm] = a.x;
                As[q * 4 + 1][mm] = a.y;
                As[q * 4 + 2][mm] = a.z;
                As[q * 4 + 3][mm] = a.w;
            }
        }
        {
            int j4 = t & 31;
            int k = t >> 5;  // 0..7
#pragma unroll
            for (int p = 0; p < 4; p++) {
                int kr = k + p * 8;
                reinterpret_cast<float4*>(&Bs[kr][0])[j4] =
                    reinterpret_cast<const float4*>(&W[(kk + kr) * 128])[j4];
            }
        }
        __syncthreads();
#pragma unroll
        for (int k = 0; k < 32; k++) {
            const float4 a = *reinterpret_cast<const float4*>(&As[k][ty * 4]);
            const float4 p = *reinterpret_cast<const float4*>(&Bs[k][tx * 8]);
            const float4 q = *reinterpret_cast<const float4*>(&Bs[k][tx * 8 + 4]);
            float av[4] = {a.x, a.y, a.z, a.w};
            float bv[8] = {p.x, p.y, p.z, p.w, q.x, q.y, q.z, q.w};
#pragma unroll
            for (int i = 0; i < 4; i++)
#pragma unroll
                for (int j = 0; j < 8; j++) acc[i][j] = fmaf(av[i], bv[j], acc[i][j]);
        }
        __syncthreads();
    }

    float bv[8];
    if (MODE == 1) {
#pragma unroll
        for (int j = 0; j < 8; j++) bv[j] = bias[tx * 8 + j];
    }
#pragma unroll
    for (int i = 0; i < 4; i++) {
        int row = m0 + ty * 4 + i;
        if (row < NN) {
            float o[8];
            if (MODE == 0) {
                float s = dinv[row];
#pragma unroll
                for (int j = 0; j < 8; j++) o[j] = s * acc[i][j];
            } else {
#pragma unroll
                for (int j = 0; j < 8; j++) o[j] = fmaxf(acc[i][j] + bv[j], 0.f);
            }
            float4 o0 = make_float4(o[0], o[1], o[2], o[3]);
            float4 o1 = make_float4(o[4], o[5], o[6], o[7]);
            *reinterpret_cast<float4*>(&out[row * 128 + tx * 8]) = o0;
            *reinterpret_cast<float4*>(&out[row * 128 + tx * 8 + 4]) = o1;
        }
    }
}

// ---------------- lin2: out[v] = h[v] @ W2 + b2  (128 -> 2) ----------------
__global__ void k_lin2(const float* __restrict__ h, const float* __restrict__ w2,
                       const float* __restrict__ b2, float* __restrict__ out) {
    int wave = threadIdx.x >> 6, lane = threadIdx.x & 63;
    int v = blockIdx.x * 4 + wave;
    if (v >= NN) return;
    float h0 = h[v * 128 + lane], h1 = h[v * 128 + 64 + lane];
    float d0 = h0 * w2[lane * 2 + 0] + h1 * w2[(lane + 64) * 2 + 0];
    float d1 = h0 * w2[lane * 2 + 1] + h1 * w2[(lane + 64) * 2 + 1];
    for (int off = 32; off; off >>= 1) {
        d0 += __shfl_down(d0, off);
        d1 += __shfl_down(d1, off);
    }
    if (lane == 0) {
        out[v * 2 + 0] = d0 + b2[0];
        out[v * 2 + 1] = d1 + b2[1];
    }
}

extern "C" void kernel_launch(void* const* d_in, const int* in_sizes, int n_in,
                              void* d_out, int out_size, void* d_ws, size_t ws_size,
                              hipStream_t stream) {
    const int*   x_idx  = (const int*)d_in[0];
    const int*   ei     = (const int*)d_in[1];
    const float* ew     = (const float*)d_in[2];
    const float* emb    = (const float*)d_in[3];
    const float* conv_w = (const float*)d_in[4];
    const float* conv_b = (const float*)d_in[5];
    const float* lin1_w = (const float*)d_in[6];
    const float* lin1_b = (const float*)d_in[7];
    const float* lin2_w = (const float*)d_in[8];
    const float* lin2_b = (const float*)d_in[9];
    float* out = (float*)d_out;

    char* ws = (char*)d_ws;
    size_t off = 0;
    auto alloc = [&](size_t bytes) -> void* {
        void* p = ws + off;
        off += (bytes + 255) & ~(size_t)255;
        return p;
    };
    float* deg     = (float*)alloc(NN * 4);
    float* dinv    = (float*)alloc(NN * 4);
    int*   cnt     = (int*)alloc(NN * 4);
    int*   rowptr  = (int*)alloc((NN + 1) * 4);
    int*   cursor  = (int*)alloc(NN * 4);
    int*   bsum    = (int*)alloc(512 * 4);
    int*   boff    = (int*)alloc(512 * 4);
    int2*  csr0    = (int2*)alloc((size_t)NE * 8);
    int2*  csr12   = (int2*)alloc((size_t)NE * 8);
    float* embw    = (float*)alloc(128 * 128 * 4);
    float* bufA    = (float*)alloc((size_t)NN * CC * 4);
    float* bufB    = (float*)alloc((size_t)NN * CC * 4);
    (void)ws_size;

    const int NBn = (NN + 255) / 256;       // 391
    const int NBe = (NE + 255) / 256;       // 6250

    k_init<<<NBn, 256, 0, stream>>>(deg, cnt);
    k_deg_count<<<NBe, 256, 0, stream>>>(ei, ew, deg, cnt);
    k_dinv<<<NBn, 256, 0, stream>>>(deg, dinv);
    k_scan1<<<NB_SCAN, 256, 0, stream>>>(cnt, rowptr, bsum);
    k_scan2<<<1, 512, 0, stream>>>(bsum, boff);
    k_scan3<<<NBn, 256, 0, stream>>>(rowptr, boff, cursor);
    k_fill<<<NBe, 256, 0, stream>>>(ei, ew, x_idx, dinv, cursor, csr0, csr12);

    // layer 0: GEMM collapses to embw = emb @ W0; agg gathers straight from embw
    k_embw<<<64, 256, 0, stream>>>(emb, conv_w, embw);
    k_agg0<<<NN / 4, 256, 0, stream>>>(csr0, rowptr, x_idx, dinv, embw,
                                       conv_b + 0 * CC, bufB);
    // layer 1: y2 = dinv*(x2 @ W1)
    k_gemm<0><<<(NN + 63) / 64, 256, 0, stream>>>(bufB, conv_w + 1 * CC * CC, dinv,
                                                  nullptr, bufA);
    k_agg<<<NN / 4, 256, 0, stream>>>(bufA, rowptr, csr12, dinv,
                                      conv_b + 1 * CC, bufB, 1);
    // layer 2: y3 = dinv*(x3 @ W2)
    k_gemm<0><<<(NN + 63) / 64, 256, 0, stream>>>(bufB, conv_w + 2 * CC * CC, dinv,
                                                  nullptr, bufA);
    k_agg<<<NN / 4, 256, 0, stream>>>(bufA, rowptr, csr12, dinv,
                                      conv_b + 2 * CC, bufB, 0);
    // lin1: h = relu(x4 @ lin1_w + lin1_b)
    k_gemm<1><<<(NN + 63) / 64, 256, 0, stream>>>(bufB, lin1_w, nullptr, lin1_b, bufA);
    // lin2
    k_lin2<<<NN / 4, 256, 0, stream>>>(bufA, lin2_w, lin2_b, out);
}

// Round 3
// 524.226 us; speedup vs baseline: 1.8598x; 1.4272x over previous
//
#include <hip/hip_runtime.h>
#include <hip/hip_fp16.h>

#define NN 100000
#define NE 1600000
#define CC 128
#define NB_SCAN 391   // ceil(NN/256)

// ---------------- init ----------------
__global__ void k_init(int* cnt) {
    int i = blockIdx.x * 256 + threadIdx.x;
    if (i < NN) cnt[i] = 0;
}

// one atomic per edge; returned value = slot within dst bucket
__global__ void k_count(const int* __restrict__ ei, int* cnt, int* loc) {
    int e = blockIdx.x * 256 + threadIdx.x;
    if (e < NE) {
        int c = ei[NE + e];
        loc[e] = atomicAdd(&cnt[c], 1);
    }
}

// ---------------- prefix scan (counts -> rowptr) ----------------
__global__ void k_scan1(const int* __restrict__ cnt, int* rowptr, int* bsum) {
    __shared__ int s[256];
    int t = threadIdx.x;
    int i = blockIdx.x * 256 + t;
    int v = (i < NN) ? cnt[i] : 0;
    s[t] = v; __syncthreads();
    for (int off = 1; off < 256; off <<= 1) {
        int x = (t >= off) ? s[t - off] : 0;
        __syncthreads();
        s[t] += x;
        __syncthreads();
    }
    if (i < NN) rowptr[i] = s[t] - v;         // exclusive
    if (t == 255) bsum[blockIdx.x] = s[255];  // block total
}

__global__ void k_scan2(const int* __restrict__ bsum, int* boff) {
    __shared__ int s[512];
    int t = threadIdx.x;
    int v = (t < NB_SCAN) ? bsum[t] : 0;
    s[t] = v; __syncthreads();
    for (int off = 1; off < 512; off <<= 1) {
        int x = (t >= off) ? s[t - off] : 0;
        __syncthreads();
        s[t] += x;
        __syncthreads();
    }
    if (t < NB_SCAN) boff[t] = s[t] - v;      // exclusive
}

__global__ void k_scan3(int* rowptr, const int* __restrict__ boff) {
    int i = blockIdx.x * 256 + threadIdx.x;
    if (i < NN) rowptr[i] += boff[i >> 8];
    if (i == 0) rowptr[NN] = NE;
}

// atomic-free CSR scatter
__global__ void k_scatter(const int* __restrict__ ei, const float* __restrict__ ew,
                          const int* __restrict__ loc, const int* __restrict__ rowptr,
                          int2* __restrict__ csr) {
    int e = blockIdx.x * 256 + threadIdx.x;
    if (e < NE) {
        int c = ei[NE + e];
        int pos = rowptr[c] + loc[e];
        csr[pos] = make_int2(ei[e], __float_as_int(ew[e]));
    }
}

// deg[v] = 1 + sum of row weights (sequential reads, no atomics); dinv = rsqrt
__global__ void k_degdinv(const int* __restrict__ rowptr, const int2* __restrict__ csr,
                          float* __restrict__ dinv) {
    int v = blockIdx.x * 256 + threadIdx.x;
    if (v < NN) {
        int b = rowptr[v], e = rowptr[v + 1];
        float s = 1.f;
        for (int i = b; i < e; i++) s += __int_as_float(csr[i].y);
        dinv[v] = rsqrtf(s);
    }
}

// ---------------- embW0 = emb @ W0 (128x128x128, tiny) ----------------
__global__ void k_embw(const float* __restrict__ emb, const float* __restrict__ w0,
                       float* embw) {
    int t = blockIdx.x * 256 + threadIdx.x;  // 16384 threads
    int i = t >> 7, j = t & 127;
    float acc = 0.f;
    for (int k = 0; k < 128; k++) acc = fmaf(emb[i * 128 + k], w0[k * 128 + j], acc);
    embw[t] = acc;
}

// ---------------- layer-0 aggregation (gathers from L2-resident tables) ----
// xout[v] = relu(dinv[v]*(sum_e w_e*dinv[src]*embw[xidx[src]] + dinv[v]*embw[xidx[v]]) + b)
__global__ void k_agg0(const int2* __restrict__ csr, const int* __restrict__ rowptr,
                       const int* __restrict__ xidx, const float* __restrict__ dinv,
                       const float* __restrict__ embw, const float* __restrict__ bias,
                       float* __restrict__ xout) {
    int wave = threadIdx.x >> 6, lane = threadIdx.x & 63;
    int v = blockIdx.x * 4 + wave;
    if (v >= NN) return;
    int beg = rowptr[v], end = rowptr[v + 1];
    const float2* e2 = reinterpret_cast<const float2*>(embw);
    float ax = 0.f, ay = 0.f;
    int e = beg;
    while (e + 8 <= end) {
        int2 c[8]; float w[8]; int r[8]; float2 t[8];
#pragma unroll
        for (int u = 0; u < 8; u++) c[u] = csr[e + u];
#pragma unroll
        for (int u = 0; u < 8; u++) { r[u] = xidx[c[u].x]; w[u] = dinv[c[u].x]; }
#pragma unroll
        for (int u = 0; u < 8; u++) t[u] = e2[r[u] * 64 + lane];
#pragma unroll
        for (int u = 0; u < 8; u++) {
            float ws = __int_as_float(c[u].y) * w[u];
            ax = fmaf(ws, t[u].x, ax);
            ay = fmaf(ws, t[u].y, ay);
        }
        e += 8;
    }
    for (; e < end; ++e) {
        int2 c = csr[e];
        int r = xidx[c.x];
        float ws = __int_as_float(c.y) * dinv[c.x];
        float2 t = e2[r * 64 + lane];
        ax = fmaf(ws, t.x, ax);
        ay = fmaf(ws, t.y, ay);
    }
    float dv = dinv[v];
    float2 ts = e2[xidx[v] * 64 + lane];   // self loop
    ax = fmaf(dv, ts.x, ax);
    ay = fmaf(dv, ts.y, ay);
    float2 b = reinterpret_cast<const float2*>(bias)[lane];
    float ox = fmaxf(fmaf(dv, ax, b.x), 0.f);
    float oy = fmaxf(fmaf(dv, ay, b.y), 0.f);
    reinterpret_cast<float2*>(xout)[v * 64 + lane] = make_float2(ox, oy);
}

// ---------------- aggregation over fp16 y ----------------
// xout[v] = relu?(dinv[v]*(sum_e w*y[src] + y[v]) + b)
__global__ void k_agg(const __half2* __restrict__ y2, const int* __restrict__ rowptr,
                      const int2* __restrict__ csr, const float* __restrict__ dinv,
                      const float* __restrict__ bias, float* __restrict__ xout,
                      int relu) {
    int wave = threadIdx.x >> 6, lane = threadIdx.x & 63;
    int v = blockIdx.x * 4 + wave;
    if (v >= NN) return;
    int beg = rowptr[v], end = rowptr[v + 1];
    float ax = 0.f, ay = 0.f;
    int e = beg;
    while (e + 8 <= end) {
        int2 c[8]; __half2 t[8];
#pragma unroll
        for (int u = 0; u < 8; u++) c[u] = csr[e + u];
#pragma unroll
        for (int u = 0; u < 8; u++) t[u] = y2[c[u].x * 64 + lane];
#pragma unroll
        for (int u = 0; u < 8; u++) {
            float w = __int_as_float(c[u].y);
            float2 f = __half22float2(t[u]);
            ax = fmaf(w, f.x, ax);
            ay = fmaf(w, f.y, ay);
        }
        e += 8;
    }
    if (e + 4 <= end) {
        int2 c[4]; __half2 t[4];
#pragma unroll
        for (int u = 0; u < 4; u++) c[u] = csr[e + u];
#pragma unroll
        for (int u = 0; u < 4; u++) t[u] = y2[c[u].x * 64 + lane];
#pragma unroll
        for (int u = 0; u < 4; u++) {
            float w = __int_as_float(c[u].y);
            float2 f = __half22float2(t[u]);
            ax = fmaf(w, f.x, ax);
            ay = fmaf(w, f.y, ay);
        }
        e += 4;
    }
    for (; e < end; ++e) {
        int2 c = csr[e];
        float w = __int_as_float(c.y);
        float2 f = __half22float2(y2[c.x * 64 + lane]);
        ax = fmaf(w, f.x, ax);
        ay = fmaf(w, f.y, ay);
    }
    float2 self = __half22float2(y2[v * 64 + lane]);
    ax += self.x; ay += self.y;
    float s = dinv[v];
    float2 b = reinterpret_cast<const float2*>(bias)[lane];
    float ox = fmaf(s, ax, b.x);
    float oy = fmaf(s, ay, b.y);
    if (relu) { ox = fmaxf(ox, 0.f); oy = fmaxf(oy, 0.f); }
    reinterpret_cast<float2*>(xout)[v * 64 + lane] = make_float2(ox, oy);
}

// ---------------- GEMM ----------------
// MODE 0: yh[n][j] = fp16( dinv[n] * dot )
// MODE 1: fused head: h = relu(dot + bias); out[n][0:2] = h @ w2 + b2
template <int MODE>
__global__ __launch_bounds__(256) void k_gemm(const float* __restrict__ A,
                                              const float* __restrict__ W,
                                              const float* __restrict__ dinv,
                                              const float* __restrict__ bias,
                                              __half* __restrict__ outh,
                                              const float* __restrict__ w2,
                                              const float* __restrict__ b2,
                                              float* __restrict__ outf) {
    __shared__ float As[32][68];    // [k][m], padded
    __shared__ float Bs[32][128];   // [k][j]
    int t = threadIdx.x;
    int tx = t & 15, ty = t >> 4;
    int m0 = blockIdx.x * 64;

    float acc[4][8];
#pragma unroll
    for (int i = 0; i < 4; i++)
#pragma unroll
        for (int j = 0; j < 8; j++) acc[i][j] = 0.f;

    for (int kk = 0; kk < 128; kk += 32) {
        {
            int q = t & 7;   // float4 index along k
            int m = t >> 3;  // 0..31
#pragma unroll
            for (int p = 0; p < 2; p++) {
                int mm = m + p * 32;
                int row = m0 + mm;
                float4 a = (row < NN)
                               ? reinterpret_cast<const float4*>(&A[row * 128 + kk])[q]
                               : make_float4(0.f, 0.f, 0.f, 0.f);
                As[q * 4 + 0][mm] = a.x;
                As[q * 4 + 1][mm] = a.y;
                As[q * 4 + 2][mm] = a.z;
                As[q * 4 + 3][mm] = a.w;
            }
        }
        {
            int j4 = t & 31;
            int k = t >> 5;  // 0..7
#pragma unroll
            for (int p = 0; p < 4; p++) {
                int kr = k + p * 8;
                reinterpret_cast<float4*>(&Bs[kr][0])[j4] =
                    reinterpret_cast<const float4*>(&W[(kk + kr) * 128])[j4];
            }
        }
        __syncthreads();
#pragma unroll
        for (int k = 0; k < 32; k++) {
            const float4 a = *reinterpret_cast<const float4*>(&As[k][ty * 4]);
            const float4 p = *reinterpret_cast<const float4*>(&Bs[k][tx * 8]);
            const float4 q = *reinterpret_cast<const float4*>(&Bs[k][tx * 8 + 4]);
            float av[4] = {a.x, a.y, a.z, a.w};
            float bv[8] = {p.x, p.y, p.z, p.w, q.x, q.y, q.z, q.w};
#pragma unroll
            for (int i = 0; i < 4; i++)
#pragma unroll
                for (int j = 0; j < 8; j++) acc[i][j] = fmaf(av[i], bv[j], acc[i][j]);
        }
        __syncthreads();
    }

    if (MODE == 0) {
#pragma unroll
        for (int i = 0; i < 4; i++) {
            int row = m0 + ty * 4 + i;
            if (row < NN) {
                float s = dinv[row];
                __half h[8];
#pragma unroll
                for (int j = 0; j < 8; j++) h[j] = __float2half(s * acc[i][j]);
                *reinterpret_cast<float4*>(&outh[row * 128 + tx * 8]) =
                    *reinterpret_cast<float4*>(h);
            }
        }
    } else {
        float bv[8], w20[8], w21[8];
#pragma unroll
        for (int j = 0; j < 8; j++) {
            bv[j] = bias[tx * 8 + j];
            w20[j] = w2[(tx * 8 + j) * 2 + 0];
            w21[j] = w2[(tx * 8 + j) * 2 + 1];
        }
        float bb0 = b2[0], bb1 = b2[1];
#pragma unroll
        for (int i = 0; i < 4; i++) {
            int row = m0 + ty * 4 + i;
            float p0 = 0.f, p1 = 0.f;
#pragma unroll
            for (int j = 0; j < 8; j++) {
                float h = fmaxf(acc[i][j] + bv[j], 0.f);
                p0 = fmaf(h, w20[j], p0);
                p1 = fmaf(h, w21[j], p1);
            }
#pragma unroll
            for (int off = 8; off; off >>= 1) {
                p0 += __shfl_down(p0, off, 16);
                p1 += __shfl_down(p1, off, 16);
            }
            if (tx == 0 && row < NN) {
                outf[row * 2 + 0] = p0 + bb0;
                outf[row * 2 + 1] = p1 + bb1;
            }
        }
    }
}

extern "C" void kernel_launch(void* const* d_in, const int* in_sizes, int n_in,
                              void* d_out, int out_size, void* d_ws, size_t ws_size,
                              hipStream_t stream) {
    const int*   x_idx  = (const int*)d_in[0];
    const int*   ei     = (const int*)d_in[1];
    const float* ew     = (const float*)d_in[2];
    const float* emb    = (const float*)d_in[3];
    const float* conv_w = (const float*)d_in[4];
    const float* conv_b = (const float*)d_in[5];
    const float* lin1_w = (const float*)d_in[6];
    const float* lin1_b = (const float*)d_in[7];
    const float* lin2_w = (const float*)d_in[8];
    const float* lin2_b = (const float*)d_in[9];
    float* out = (float*)d_out;

    char* ws = (char*)d_ws;
    size_t off = 0;
    auto alloc = [&](size_t bytes) -> void* {
        void* p = ws + off;
        off += (bytes + 255) & ~(size_t)255;
        return p;
    };
    float*  dinv   = (float*)alloc(NN * 4);
    int*    cnt    = (int*)alloc(NN * 4);
    int*    rowptr = (int*)alloc((NN + 1) * 4);
    int*    bsum   = (int*)alloc(512 * 4);
    int*    boff   = (int*)alloc(512 * 4);
    int*    loc    = (int*)alloc((size_t)NE * 4);
    int2*   csr    = (int2*)alloc((size_t)NE * 8);
    float*  embw   = (float*)alloc(128 * 128 * 4);
    float*  xbuf   = (float*)alloc((size_t)NN * CC * 4);
    __half* ybuf   = (__half*)alloc((size_t)NN * CC * 2);
    (void)ws_size;

    const int NBn = (NN + 255) / 256;       // 391
    const int NBe = (NE + 255) / 256;       // 6250

    k_init<<<NBn, 256, 0, stream>>>(cnt);
    k_count<<<NBe, 256, 0, stream>>>(ei, cnt, loc);
    k_scan1<<<NB_SCAN, 256, 0, stream>>>(cnt, rowptr, bsum);
    k_scan2<<<1, 512, 0, stream>>>(bsum, boff);
    k_scan3<<<NBn, 256, 0, stream>>>(rowptr, boff);
    k_scatter<<<NBe, 256, 0, stream>>>(ei, ew, loc, rowptr, csr);
    k_degdinv<<<NBn, 256, 0, stream>>>(rowptr, csr, dinv);

    // layer 0: embw = emb @ W0; fused gather-aggregate
    k_embw<<<64, 256, 0, stream>>>(emb, conv_w, embw);
    k_agg0<<<NN / 4, 256, 0, stream>>>(csr, rowptr, x_idx, dinv, embw,
                                       conv_b + 0 * CC, xbuf);
    // layer 1
    k_gemm<0><<<(NN + 63) / 64, 256, 0, stream>>>(xbuf, conv_w + 1 * CC * CC, dinv,
                                                  nullptr, ybuf, nullptr, nullptr,
                                                  nullptr);
    k_agg<<<NN / 4, 256, 0, stream>>>((const __half2*)ybuf, rowptr, csr, dinv,
                                      conv_b + 1 * CC, xbuf, 1);
    // layer 2
    k_gemm<0><<<(NN + 63) / 64, 256, 0, stream>>>(xbuf, conv_w + 2 * CC * CC, dinv,
                                                  nullptr, ybuf, nullptr, nullptr,
                                                  nullptr);
    k_agg<<<NN / 4, 256, 0, stream>>>((const __half2*)ybuf, rowptr, csr, dinv,
                                      conv_b + 2 * CC, xbuf, 0);
    // head: relu(x @ lin1_w + lin1_b) @ lin2_w + lin2_b, fused
    k_gemm<1><<<(NN + 63) / 64, 256, 0, stream>>>(xbuf, lin1_w, nullptr, lin1_b,
                                                  nullptr, lin2_w, lin2_b, out);
}

// Round 4
// 481.616 us; speedup vs baseline: 2.0244x; 1.0885x over previous
//
#include <hip/hip_runtime.h>
#include <hip/hip_fp16.h>

#define NN 100000
#define NE 1600000
#define CC 128
#define NB_SCAN 391   // ceil(NN/256)

// ---------------- init ----------------
__global__ void k_init(int* cnt) {
    int i = blockIdx.x * 256 + threadIdx.x;
    if (i < NN) cnt[i] = 0;
}

// one atomic per edge; returned value = slot within dst bucket
__global__ void k_count(const int* __restrict__ ei, int* cnt, int* loc) {
    int e = blockIdx.x * 256 + threadIdx.x;
    if (e < NE) {
        int c = ei[NE + e];
        loc[e] = atomicAdd(&cnt[c], 1);
    }
}

// ---------------- prefix scan (counts -> rowptr) ----------------
__global__ void k_scan1(const int* __restrict__ cnt, int* rowptr, int* bsum) {
    __shared__ int s[256];
    int t = threadIdx.x;
    int i = blockIdx.x * 256 + t;
    int v = (i < NN) ? cnt[i] : 0;
    s[t] = v; __syncthreads();
    for (int off = 1; off < 256; off <<= 1) {
        int x = (t >= off) ? s[t - off] : 0;
        __syncthreads();
        s[t] += x;
        __syncthreads();
    }
    if (i < NN) rowptr[i] = s[t] - v;         // exclusive
    if (t == 255) bsum[blockIdx.x] = s[255];  // block total
}

__global__ void k_scan2(const int* __restrict__ bsum, int* boff) {
    __shared__ int s[512];
    int t = threadIdx.x;
    int v = (t < NB_SCAN) ? bsum[t] : 0;
    s[t] = v; __syncthreads();
    for (int off = 1; off < 512; off <<= 1) {
        int x = (t >= off) ? s[t - off] : 0;
        __syncthreads();
        s[t] += x;
        __syncthreads();
    }
    if (t < NB_SCAN) boff[t] = s[t] - v;      // exclusive
}

__global__ void k_scan3(int* rowptr, const int* __restrict__ boff) {
    int i = blockIdx.x * 256 + threadIdx.x;
    if (i < NN) rowptr[i] += boff[i >> 8];
    if (i == 0) rowptr[NN] = NE;
}

// atomic-free CSR scatter
__global__ void k_scatter(const int* __restrict__ ei, const float* __restrict__ ew,
                          const int* __restrict__ loc, const int* __restrict__ rowptr,
                          int2* __restrict__ csr) {
    int e = blockIdx.x * 256 + threadIdx.x;
    if (e < NE) {
        int c = ei[NE + e];
        int pos = rowptr[c] + loc[e];
        csr[pos] = make_int2(ei[e], __float_as_int(ew[e]));
    }
}

// deg[v] = 1 + sum of row weights (sequential reads, no atomics); dinv = rsqrt
__global__ void k_degdinv(const int* __restrict__ rowptr, const int2* __restrict__ csr,
                          float* __restrict__ dinv) {
    int v = blockIdx.x * 256 + threadIdx.x;
    if (v < NN) {
        int b = rowptr[v], e = rowptr[v + 1];
        float s = 1.f;
        for (int i = b; i < e; i++) s += __int_as_float(csr[i].y);
        dinv[v] = rsqrtf(s);
    }
}

// csr0[pos] = {emb_row(src), w*dinv[src]} — removes the dependent index chain
// from the layer-0 aggregation.
__global__ void k_mkcsr0(const int2* __restrict__ csr, const int* __restrict__ xidx,
                         const float* __restrict__ dinv, int2* __restrict__ csr0) {
    int e = blockIdx.x * 256 + threadIdx.x;
    if (e < NE) {
        int2 c = csr[e];
        csr0[e] = make_int2(xidx[c.x],
                            __float_as_int(__int_as_float(c.y) * dinv[c.x]));
    }
}

// ---------------- embW0 = emb @ W0, stored fp16 (32KB, L1-resident) ----------
__global__ void k_embw(const float* __restrict__ emb, const float* __restrict__ w0,
                       __half2* __restrict__ ewh) {
    int t = blockIdx.x * 256 + threadIdx.x;  // 8192 threads
    int i = t >> 6, jp = t & 63;
    int j0 = jp * 2;
    float a0 = 0.f, a1 = 0.f;
    for (int k = 0; k < 128; k++) {
        float e = emb[i * 128 + k];
        a0 = fmaf(e, w0[k * 128 + j0], a0);
        a1 = fmaf(e, w0[k * 128 + j0 + 1], a1);
    }
    ewh[t] = __floats2half2_rn(a0, a1);
}

// ---------------- layer-0 aggregation (gathers from 32KB L1-resident table) --
// xout[v] = relu(dinv[v]*(sum_e ws_e*ewh[row_e] + dinv[v]*ewh[xidx[v]]) + b)
__global__ void k_agg0(const int2* __restrict__ csr0, const int* __restrict__ rowptr,
                       const int* __restrict__ xidx, const float* __restrict__ dinv,
                       const __half2* __restrict__ ewh, const float* __restrict__ bias,
                       float* __restrict__ xout) {
    int wave = threadIdx.x >> 6, lane = threadIdx.x & 63;
    int v = blockIdx.x * 4 + wave;
    if (v >= NN) return;
    int beg = rowptr[v], end = rowptr[v + 1];
    float ax = 0.f, ay = 0.f;
    int e = beg;
    while (e + 8 <= end) {
        int2 c[8]; __half2 t[8];
#pragma unroll
        for (int u = 0; u < 8; u++) c[u] = csr0[e + u];
#pragma unroll
        for (int u = 0; u < 8; u++) t[u] = ewh[c[u].x * 64 + lane];
#pragma unroll
        for (int u = 0; u < 8; u++) {
            float w = __int_as_float(c[u].y);
            float2 f = __half22float2(t[u]);
            ax = fmaf(w, f.x, ax);
            ay = fmaf(w, f.y, ay);
        }
        e += 8;
    }
    if (e + 4 <= end) {
        int2 c[4]; __half2 t[4];
#pragma unroll
        for (int u = 0; u < 4; u++) c[u] = csr0[e + u];
#pragma unroll
        for (int u = 0; u < 4; u++) t[u] = ewh[c[u].x * 64 + lane];
#pragma unroll
        for (int u = 0; u < 4; u++) {
            float w = __int_as_float(c[u].y);
            float2 f = __half22float2(t[u]);
            ax = fmaf(w, f.x, ax);
            ay = fmaf(w, f.y, ay);
        }
        e += 4;
    }
    for (; e < end; ++e) {
        int2 c = csr0[e];
        float w = __int_as_float(c.y);
        float2 f = __half22float2(ewh[c.x * 64 + lane]);
        ax = fmaf(w, f.x, ax);
        ay = fmaf(w, f.y, ay);
    }
    float dv = dinv[v];
    float2 ts = __half22float2(ewh[xidx[v] * 64 + lane]);  // self loop
    ax = fmaf(dv, ts.x, ax);
    ay = fmaf(dv, ts.y, ay);
    float2 b = reinterpret_cast<const float2*>(bias)[lane];
    float ox = fmaxf(fmaf(dv, ax, b.x), 0.f);
    float oy = fmaxf(fmaf(dv, ay, b.y), 0.f);
    reinterpret_cast<float2*>(xout)[v * 64 + lane] = make_float2(ox, oy);
}

// ---------------- aggregation over fp16 y ----------------
// xout[v] = relu?(dinv[v]*(sum_e w*y[src] + y[v]) + b)
__global__ void k_agg(const __half2* __restrict__ y2, const int* __restrict__ rowptr,
                      const int2* __restrict__ csr, const float* __restrict__ dinv,
                      const float* __restrict__ bias, float* __restrict__ xout,
                      int relu) {
    int wave = threadIdx.x >> 6, lane = threadIdx.x & 63;
    int v = blockIdx.x * 4 + wave;
    if (v >= NN) return;
    int beg = rowptr[v], end = rowptr[v + 1];
    float ax = 0.f, ay = 0.f;
    int e = beg;
    while (e + 8 <= end) {
        int2 c[8]; __half2 t[8];
#pragma unroll
        for (int u = 0; u < 8; u++) c[u] = csr[e + u];
#pragma unroll
        for (int u = 0; u < 8; u++) t[u] = y2[c[u].x * 64 + lane];
#pragma unroll
        for (int u = 0; u < 8; u++) {
            float w = __int_as_float(c[u].y);
            float2 f = __half22float2(t[u]);
            ax = fmaf(w, f.x, ax);
            ay = fmaf(w, f.y, ay);
        }
        e += 8;
    }
    if (e + 4 <= end) {
        int2 c[4]; __half2 t[4];
#pragma unroll
        for (int u = 0; u < 4; u++) c[u] = csr[e + u];
#pragma unroll
        for (int u = 0; u < 4; u++) t[u] = y2[c[u].x * 64 + lane];
#pragma unroll
        for (int u = 0; u < 4; u++) {
            float w = __int_as_float(c[u].y);
            float2 f = __half22float2(t[u]);
            ax = fmaf(w, f.x, ax);
            ay = fmaf(w, f.y, ay);
        }
        e += 4;
    }
    for (; e < end; ++e) {
        int2 c = csr[e];
        float w = __int_as_float(c.y);
        float2 f = __half22float2(y2[c.x * 64 + lane]);
        ax = fmaf(w, f.x, ax);
        ay = fmaf(w, f.y, ay);
    }
    float2 self = __half22float2(y2[v * 64 + lane]);
    ax += self.x; ay += self.y;
    float s = dinv[v];
    float2 b = reinterpret_cast<const float2*>(bias)[lane];
    float ox = fmaf(s, ax, b.x);
    float oy = fmaf(s, ay, b.y);
    if (relu) { ox = fmaxf(ox, 0.f); oy = fmaxf(oy, 0.f); }
    reinterpret_cast<float2*>(xout)[v * 64 + lane] = make_float2(ox, oy);
}

// ---------------- GEMM ----------------
// MODE 0: yh[n][j] = fp16( dinv[n] * dot )
// MODE 1: fused head: h = relu(dot + bias); out[n][0:2] = h @ w2 + b2
template <int MODE>
__global__ __launch_bounds__(256) void k_gemm(const float* __restrict__ A,
                                              const float* __restrict__ W,
                                              const float* __restrict__ dinv,
                                              const float* __restrict__ bias,
                                              __half* __restrict__ outh,
                                              const float* __restrict__ w2,
                                              const float* __restrict__ b2,
                                              float* __restrict__ outf) {
    __shared__ float As[32][68];    // [k][m], padded
    __shared__ float Bs[32][128];   // [k][j]
    int t = threadIdx.x;
    int tx = t & 15, ty = t >> 4;
    int m0 = blockIdx.x * 64;

    float acc[4][8];
#pragma unroll
    for (int i = 0; i < 4; i++)
#pragma unroll
        for (int j = 0; j < 8; j++) acc[i][j] = 0.f;

    for (int kk = 0; kk < 128; kk += 32) {
        {
            int q = t & 7;   // float4 index along k
            int m = t >> 3;  // 0..31
#pragma unroll
            for (int p = 0; p < 2; p++) {
                int mm = m + p * 32;
                int row = m0 + mm;
                float4 a = (row < NN)
                               ? reinterpret_cast<const float4*>(&A[row * 128 + kk])[q]
                               : make_float4(0.f, 0.f, 0.f, 0.f);
                As[q * 4 + 0][mm] = a.x;
                As[q * 4 + 1][mm] = a.y;
                As[q * 4 + 2][mm] = a.z;
                As[q * 4 + 3][mm] = a.w;
            }
        }
        {
            int j4 = t & 31;
            int k = t >> 5;  // 0..7
#pragma unroll
            for (int p = 0; p < 4; p++) {
                int kr = k + p * 8;
                reinterpret_cast<float4*>(&Bs[kr][0])[j4] =
                    reinterpret_cast<const float4*>(&W[(kk + kr) * 128])[j4];
            }
        }
        __syncthreads();
#pragma unroll
        for (int k = 0; k < 32; k++) {
            const float4 a = *reinterpret_cast<const float4*>(&As[k][ty * 4]);
            const float4 p = *reinterpret_cast<const float4*>(&Bs[k][tx * 8]);
            const float4 q = *reinterpret_cast<const float4*>(&Bs[k][tx * 8 + 4]);
            float av[4] = {a.x, a.y, a.z, a.w};
            float bv[8] = {p.x, p.y, p.z, p.w, q.x, q.y, q.z, q.w};
#pragma unroll
            for (int i = 0; i < 4; i++)
#pragma unroll
                for (int j = 0; j < 8; j++) acc[i][j] = fmaf(av[i], bv[j], acc[i][j]);
        }
        __syncthreads();
    }

    if (MODE == 0) {
#pragma unroll
        for (int i = 0; i < 4; i++) {
            int row = m0 + ty * 4 + i;
            if (row < NN) {
                float s = dinv[row];
                __half h[8];
#pragma unroll
                for (int j = 0; j < 8; j++) h[j] = __float2half(s * acc[i][j]);
                *reinterpret_cast<float4*>(&outh[row * 128 + tx * 8]) =
                    *reinterpret_cast<float4*>(h);
            }
        }
    } else {
        float bv[8], w20[8], w21[8];
#pragma unroll
        for (int j = 0; j < 8; j++) {
            bv[j] = bias[tx * 8 + j];
            w20[j] = w2[(tx * 8 + j) * 2 + 0];
            w21[j] = w2[(tx * 8 + j) * 2 + 1];
        }
        float bb0 = b2[0], bb1 = b2[1];
#pragma unroll
        for (int i = 0; i < 4; i++) {
            int row = m0 + ty * 4 + i;
            float p0 = 0.f, p1 = 0.f;
#pragma unroll
            for (int j = 0; j < 8; j++) {
                float h = fmaxf(acc[i][j] + bv[j], 0.f);
                p0 = fmaf(h, w20[j], p0);
                p1 = fmaf(h, w21[j], p1);
            }
#pragma unroll
            for (int off = 8; off; off >>= 1) {
                p0 += __shfl_down(p0, off, 16);
                p1 += __shfl_down(p1, off, 16);
            }
            if (tx == 0 && row < NN) {
                outf[row * 2 + 0] = p0 + bb0;
                outf[row * 2 + 1] = p1 + bb1;
            }
        }
    }
}

extern "C" void kernel_launch(void* const* d_in, const int* in_sizes, int n_in,
                              void* d_out, int out_size, void* d_ws, size_t ws_size,
                              hipStream_t stream) {
    const int*   x_idx  = (const int*)d_in[0];
    const int*   ei     = (const int*)d_in[1];
    const float* ew     = (const float*)d_in[2];
    const float* emb    = (const float*)d_in[3];
    const float* conv_w = (const float*)d_in[4];
    const float* conv_b = (const float*)d_in[5];
    const float* lin1_w = (const float*)d_in[6];
    const float* lin1_b = (const float*)d_in[7];
    const float* lin2_w = (const float*)d_in[8];
    const float* lin2_b = (const float*)d_in[9];
    float* out = (float*)d_out;

    char* ws = (char*)d_ws;
    size_t off = 0;
    auto alloc = [&](size_t bytes) -> void* {
        void* p = ws + off;
        off += (bytes + 255) & ~(size_t)255;
        return p;
    };
    float*   dinv   = (float*)alloc(NN * 4);
    int*     cnt    = (int*)alloc(NN * 4);
    int*     rowptr = (int*)alloc((NN + 1) * 4);
    int*     bsum   = (int*)alloc(512 * 4);
    int*     boff   = (int*)alloc(512 * 4);
    int*     loc    = (int*)alloc((size_t)NE * 4);
    int2*    csr    = (int2*)alloc((size_t)NE * 8);
    int2*    csr0   = (int2*)alloc((size_t)NE * 8);
    __half2* ewh    = (__half2*)alloc(128 * 64 * 4);
    float*   xbuf   = (float*)alloc((size_t)NN * CC * 4);
    __half*  ybuf   = (__half*)alloc((size_t)NN * CC * 2);
    (void)ws_size;

    const int NBn = (NN + 255) / 256;       // 391
    const int NBe = (NE + 255) / 256;       // 6250

    k_init<<<NBn, 256, 0, stream>>>(cnt);
    k_count<<<NBe, 256, 0, stream>>>(ei, cnt, loc);
    k_scan1<<<NB_SCAN, 256, 0, stream>>>(cnt, rowptr, bsum);
    k_scan2<<<1, 512, 0, stream>>>(bsum, boff);
    k_scan3<<<NBn, 256, 0, stream>>>(rowptr, boff);
    k_scatter<<<NBe, 256, 0, stream>>>(ei, ew, loc, rowptr, csr);
    k_degdinv<<<NBn, 256, 0, stream>>>(rowptr, csr, dinv);
    k_mkcsr0<<<NBe, 256, 0, stream>>>(csr, x_idx, dinv, csr0);

    // layer 0: ewh = fp16(emb @ W0); fused gather-aggregate from L1-resident table
    k_embw<<<32, 256, 0, stream>>>(emb, conv_w, ewh);
    k_agg0<<<NN / 4, 256, 0, stream>>>(csr0, rowptr, x_idx, dinv, ewh,
                                       conv_b + 0 * CC, xbuf);
    // layer 1
    k_gemm<0><<<(NN + 63) / 64, 256, 0, stream>>>(xbuf, conv_w + 1 * CC * CC, dinv,
                                                  nullptr, ybuf, nullptr, nullptr,
                                                  nullptr);
    k_agg<<<NN / 4, 256, 0, stream>>>((const __half2*)ybuf, rowptr, csr, dinv,
                                      conv_b + 1 * CC, xbuf, 1);
    // layer 2
    k_gemm<0><<<(NN + 63) / 64, 256, 0, stream>>>(xbuf, conv_w + 2 * CC * CC, dinv,
                                                  nullptr, ybuf, nullptr, nullptr,
                                                  nullptr);
    k_agg<<<NN / 4, 256, 0, stream>>>((const __half2*)ybuf, rowptr, csr, dinv,
                                      conv_b + 2 * CC, xbuf, 0);
    // head: relu(x @ lin1_w + lin1_b) @ lin2_w + lin2_b, fused
    k_gemm<1><<<(NN + 63) / 64, 256, 0, stream>>>(xbuf, lin1_w, nullptr, lin1_b,
                                                  nullptr, lin2_w, lin2_b, out);
}

// Round 5
// 444.590 us; speedup vs baseline: 2.1930x; 1.0833x over previous
//
#include <hip/hip_runtime.h>
#include <hip/hip_fp16.h>

#define NN 100000
#define NE 1600000
#define CC 128
#define NB_SCAN 391   // ceil(NN/256)

typedef _Float16 f16x8 __attribute__((ext_vector_type(8)));
typedef float    f32x4 __attribute__((ext_vector_type(4)));

// ---------------- init ----------------
__global__ void k_init(int* cnt) {
    int i = blockIdx.x * 256 + threadIdx.x;
    if (i < NN) cnt[i] = 0;
}

// one atomic per edge; returned value = slot within dst bucket
__global__ void k_count(const int* __restrict__ ei, int* cnt, int* loc) {
    int e = blockIdx.x * 256 + threadIdx.x;
    if (e < NE) {
        int c = ei[NE + e];
        loc[e] = atomicAdd(&cnt[c], 1);
    }
}

// ---------------- prefix scan (counts -> rowptr) ----------------
__global__ void k_scan1(const int* __restrict__ cnt, int* rowptr, int* bsum) {
    __shared__ int s[256];
    int t = threadIdx.x;
    int i = blockIdx.x * 256 + t;
    int v = (i < NN) ? cnt[i] : 0;
    s[t] = v; __syncthreads();
    for (int off = 1; off < 256; off <<= 1) {
        int x = (t >= off) ? s[t - off] : 0;
        __syncthreads();
        s[t] += x;
        __syncthreads();
    }
    if (i < NN) rowptr[i] = s[t] - v;         // exclusive
    if (t == 255) bsum[blockIdx.x] = s[255];  // block total
}

__global__ void k_scan2(const int* __restrict__ bsum, int* boff) {
    __shared__ int s[512];
    int t = threadIdx.x;
    int v = (t < NB_SCAN) ? bsum[t] : 0;
    s[t] = v; __syncthreads();
    for (int off = 1; off < 512; off <<= 1) {
        int x = (t >= off) ? s[t - off] : 0;
        __syncthreads();
        s[t] += x;
        __syncthreads();
    }
    if (t < NB_SCAN) boff[t] = s[t] - v;      // exclusive
}

__global__ void k_scan3(int* rowptr, const int* __restrict__ boff) {
    int i = blockIdx.x * 256 + threadIdx.x;
    if (i < NN) rowptr[i] += boff[i >> 8];
    if (i == 0) rowptr[NN] = NE;
}

// atomic-free CSR scatter
__global__ void k_scatter(const int* __restrict__ ei, const float* __restrict__ ew,
                          const int* __restrict__ loc, const int* __restrict__ rowptr,
                          int2* __restrict__ csr) {
    int e = blockIdx.x * 256 + threadIdx.x;
    if (e < NE) {
        int c = ei[NE + e];
        int pos = rowptr[c] + loc[e];
        csr[pos] = make_int2(ei[e], __float_as_int(ew[e]));
    }
}

// deg[v] = 1 + sum of row weights (sequential reads, no atomics); dinv = rsqrt
__global__ void k_degdinv(const int* __restrict__ rowptr, const int2* __restrict__ csr,
                          float* __restrict__ dinv) {
    int v = blockIdx.x * 256 + threadIdx.x;
    if (v < NN) {
        int b = rowptr[v], e = rowptr[v + 1];
        float s = 1.f;
        for (int i = b; i < e; i++) s += __int_as_float(csr[i].y);
        dinv[v] = rsqrtf(s);
    }
}

// csr0[pos] = {emb_row(src), w*dinv[src]}
__global__ void k_mkcsr0(const int2* __restrict__ csr, const int* __restrict__ xidx,
                         const float* __restrict__ dinv, int2* __restrict__ csr0) {
    int e = blockIdx.x * 256 + threadIdx.x;
    if (e < NE) {
        int2 c = csr[e];
        csr0[e] = make_int2(xidx[c.x],
                            __float_as_int(__int_as_float(c.y) * dinv[c.x]));
    }
}

// Wt[l][j][k] = fp16(W_l[k][j])  (transposed fp16 weights for MFMA B-fragments)
__global__ void k_wcvt(const float* __restrict__ conv_w, const float* __restrict__ lin1_w,
                       _Float16* __restrict__ wt) {
    int t = blockIdx.x * 256 + threadIdx.x;  // 3*16384
    int l = t >> 14, r = t & 16383;
    int j = r >> 7, k = r & 127;
    const float* src = (l < 2) ? (conv_w + (l + 1) * 16384) : lin1_w;
    wt[l * 16384 + j * 128 + k] = (_Float16)src[k * 128 + j];
}

// ---------------- embW0 = emb @ W0, stored fp16 (32KB, L1-resident) ----------
__global__ void k_embw(const float* __restrict__ emb, const float* __restrict__ w0,
                       __half2* __restrict__ ewh) {
    int t = blockIdx.x * 256 + threadIdx.x;  // 8192 threads
    int i = t >> 6, jp = t & 63;
    int j0 = jp * 2;
    float a0 = 0.f, a1 = 0.f;
    for (int k = 0; k < 128; k++) {
        float e = emb[i * 128 + k];
        a0 = fmaf(e, w0[k * 128 + j0], a0);
        a1 = fmaf(e, w0[k * 128 + j0 + 1], a1);
    }
    ewh[t] = __floats2half2_rn(a0, a1);
}

// ---------------- layer-0 aggregation (gathers from 32KB L1-resident table) --
__global__ void k_agg0(const int2* __restrict__ csr0, const int* __restrict__ rowptr,
                       const int* __restrict__ xidx, const float* __restrict__ dinv,
                       const __half2* __restrict__ ewh, const float* __restrict__ bias,
                       __half2* __restrict__ xout) {
    int wave = threadIdx.x >> 6, lane = threadIdx.x & 63;
    int v = blockIdx.x * 4 + wave;
    if (v >= NN) return;
    int beg = rowptr[v], end = rowptr[v + 1];
    float ax = 0.f, ay = 0.f;
    int e = beg;
    while (e + 8 <= end) {
        int2 c[8]; __half2 t[8];
#pragma unroll
        for (int u = 0; u < 8; u++) c[u] = csr0[e + u];
#pragma unroll
        for (int u = 0; u < 8; u++) t[u] = ewh[c[u].x * 64 + lane];
#pragma unroll
        for (int u = 0; u < 8; u++) {
            float w = __int_as_float(c[u].y);
            float2 f = __half22float2(t[u]);
            ax = fmaf(w, f.x, ax);
            ay = fmaf(w, f.y, ay);
        }
        e += 8;
    }
    if (e + 4 <= end) {
        int2 c[4]; __half2 t[4];
#pragma unroll
        for (int u = 0; u < 4; u++) c[u] = csr0[e + u];
#pragma unroll
        for (int u = 0; u < 4; u++) t[u] = ewh[c[u].x * 64 + lane];
#pragma unroll
        for (int u = 0; u < 4; u++) {
            float w = __int_as_float(c[u].y);
            float2 f = __half22float2(t[u]);
            ax = fmaf(w, f.x, ax);
            ay = fmaf(w, f.y, ay);
        }
        e += 4;
    }
    for (; e < end; ++e) {
        int2 c = csr0[e];
        float w = __int_as_float(c.y);
        float2 f = __half22float2(ewh[c.x * 64 + lane]);
        ax = fmaf(w, f.x, ax);
        ay = fmaf(w, f.y, ay);
    }
    float dv = dinv[v];
    float2 ts = __half22float2(ewh[xidx[v] * 64 + lane]);  // self loop
    ax = fmaf(dv, ts.x, ax);
    ay = fmaf(dv, ts.y, ay);
    float2 b = reinterpret_cast<const float2*>(bias)[lane];
    float ox = fmaxf(fmaf(dv, ax, b.x), 0.f);
    float oy = fmaxf(fmaf(dv, ay, b.y), 0.f);
    xout[v * 64 + lane] = __floats2half2_rn(ox, oy);
}

// ---------------- aggregation over fp16 y, fp16 out ----------------
__global__ void k_agg(const __half2* __restrict__ y2, const int* __restrict__ rowptr,
                      const int2* __restrict__ csr, const float* __restrict__ dinv,
                      const float* __restrict__ bias, __half2* __restrict__ xout,
                      int relu) {
    int wave = threadIdx.x >> 6, lane = threadIdx.x & 63;
    int v = blockIdx.x * 4 + wave;
    if (v >= NN) return;
    int beg = rowptr[v], end = rowptr[v + 1];
    float ax = 0.f, ay = 0.f;
    int e = beg;
    while (e + 8 <= end) {
        int2 c[8]; __half2 t[8];
#pragma unroll
        for (int u = 0; u < 8; u++) c[u] = csr[e + u];
#pragma unroll
        for (int u = 0; u < 8; u++) t[u] = y2[c[u].x * 64 + lane];
#pragma unroll
        for (int u = 0; u < 8; u++) {
            float w = __int_as_float(c[u].y);
            float2 f = __half22float2(t[u]);
            ax = fmaf(w, f.x, ax);
            ay = fmaf(w, f.y, ay);
        }
        e += 8;
    }
    if (e + 4 <= end) {
        int2 c[4]; __half2 t[4];
#pragma unroll
        for (int u = 0; u < 4; u++) c[u] = csr[e + u];
#pragma unroll
        for (int u = 0; u < 4; u++) t[u] = y2[c[u].x * 64 + lane];
#pragma unroll
        for (int u = 0; u < 4; u++) {
            float w = __int_as_float(c[u].y);
            float2 f = __half22float2(t[u]);
            ax = fmaf(w, f.x, ax);
            ay = fmaf(w, f.y, ay);
        }
        e += 4;
    }
    for (; e < end; ++e) {
        int2 c = csr[e];
        float w = __int_as_float(c.y);
        float2 f = __half22float2(y2[c.x * 64 + lane]);
        ax = fmaf(w, f.x, ax);
        ay = fmaf(w, f.y, ay);
    }
    float2 self = __half22float2(y2[v * 64 + lane]);
    ax += self.x; ay += self.y;
    float s = dinv[v];
    float2 b = reinterpret_cast<const float2*>(bias)[lane];
    float ox = fmaf(s, ax, b.x);
    float oy = fmaf(s, ay, b.y);
    if (relu) { ox = fmaxf(ox, 0.f); oy = fmaxf(oy, 0.f); }
    xout[v * 64 + lane] = __floats2half2_rn(ox, oy);
}

// ---------------- MFMA fp16 GEMM: 64 rows/block, 4 waves, 16 rows/wave -------
// MODE 0: y[n][j] = fp16( dinv[n] * (A@W)[n][j] )
// MODE 1: h = relu(A@W + bias); out[n][0:2] = h @ w2 + b2
// A [NN][128] fp16 row-major; Wt [128 cols][128 k] fp16 (transposed W).
// Fragment layouts (16x16x32): A: row=lane&15, k=(lane>>4)*8+e;
// B: col=lane&15, k=(lane>>4)*8+e; D: col=lane&15, row=(lane>>4)*4+reg.
template <int MODE>
__global__ __launch_bounds__(256) void k_mgemm(const _Float16* __restrict__ A,
                                               const _Float16* __restrict__ Wt,
                                               const float* __restrict__ dinv,
                                               const float* __restrict__ bias,
                                               _Float16* __restrict__ yout,
                                               const float* __restrict__ w2,
                                               const float* __restrict__ b2,
                                               float* __restrict__ outf) {
    int wid = threadIdx.x >> 6, lane = threadIdx.x & 63;
    int lc = lane & 15, lg = lane >> 4;
    int arow = blockIdx.x * 64 + wid * 16 + lc;   // row this lane loads for A
    bool rok = arow < NN;

    f32x4 acc[8];
#pragma unroll
    for (int j = 0; j < 8; j++) acc[j] = (f32x4){0.f, 0.f, 0.f, 0.f};

#pragma unroll
    for (int kc = 0; kc < 4; kc++) {
        int k0 = kc * 32 + lg * 8;
        f16x8 a = {0, 0, 0, 0, 0, 0, 0, 0};
        if (rok) a = *reinterpret_cast<const f16x8*>(&A[arow * 128 + k0]);
#pragma unroll
        for (int j = 0; j < 8; j++) {
            f16x8 b = *reinterpret_cast<const f16x8*>(&Wt[(j * 16 + lc) * 128 + k0]);
            acc[j] = __builtin_amdgcn_mfma_f32_16x16x32_f16(a, b, acc[j], 0, 0, 0);
        }
    }

    int orow0 = blockIdx.x * 64 + wid * 16 + lg * 4;  // rows for regs r=0..3
    if (MODE == 0) {
        float dv[4];
#pragma unroll
        for (int r = 0; r < 4; r++)
            dv[r] = (orow0 + r < NN) ? dinv[orow0 + r] : 0.f;
#pragma unroll
        for (int j = 0; j < 8; j++) {
#pragma unroll
            for (int r = 0; r < 4; r++) {
                int orow = orow0 + r;
                if (orow < NN)
                    yout[orow * 128 + j * 16 + lc] = (_Float16)(dv[r] * acc[j][r]);
            }
        }
    } else {
        float bj[8], w0j[8], w1j[8];
#pragma unroll
        for (int j = 0; j < 8; j++) {
            int c = j * 16 + lc;
            bj[j] = bias[c];
            w0j[j] = w2[c * 2 + 0];
            w1j[j] = w2[c * 2 + 1];
        }
        float bb0 = b2[0], bb1 = b2[1];
#pragma unroll
        for (int r = 0; r < 4; r++) {
            float p0 = 0.f, p1 = 0.f;
#pragma unroll
            for (int j = 0; j < 8; j++) {
                float h = fmaxf(acc[j][r] + bj[j], 0.f);
                p0 = fmaf(h, w0j[j], p0);
                p1 = fmaf(h, w1j[j], p1);
            }
#pragma unroll
            for (int m = 1; m < 16; m <<= 1) {
                p0 += __shfl_xor(p0, m);
                p1 += __shfl_xor(p1, m);
            }
            int orow = orow0 + r;
            if (lc == 0 && orow < NN)
                *reinterpret_cast<float2*>(&outf[orow * 2]) =
                    make_float2(p0 + bb0, p1 + bb1);
        }
    }
}

extern "C" void kernel_launch(void* const* d_in, const int* in_sizes, int n_in,
                              void* d_out, int out_size, void* d_ws, size_t ws_size,
                              hipStream_t stream) {
    const int*   x_idx  = (const int*)d_in[0];
    const int*   ei     = (const int*)d_in[1];
    const float* ew     = (const float*)d_in[2];
    const float* emb    = (const float*)d_in[3];
    const float* conv_w = (const float*)d_in[4];
    const float* conv_b = (const float*)d_in[5];
    const float* lin1_w = (const float*)d_in[6];
    const float* lin1_b = (const float*)d_in[7];
    const float* lin2_w = (const float*)d_in[8];
    const float* lin2_b = (const float*)d_in[9];
    float* out = (float*)d_out;

    char* ws = (char*)d_ws;
    size_t off = 0;
    auto alloc = [&](size_t bytes) -> void* {
        void* p = ws + off;
        off += (bytes + 255) & ~(size_t)255;
        return p;
    };
    float*    dinv   = (float*)alloc(NN * 4);
    int*      cnt    = (int*)alloc(NN * 4);
    int*      rowptr = (int*)alloc((NN + 1) * 4);
    int*      bsum   = (int*)alloc(512 * 4);
    int*      boff   = (int*)alloc(512 * 4);
    int*      loc    = (int*)alloc((size_t)NE * 4);
    int2*     csr    = (int2*)alloc((size_t)NE * 8);
    int2*     csr0   = (int2*)alloc((size_t)NE * 8);
    __half2*  ewh    = (__half2*)alloc(128 * 64 * 4);
    _Float16* wt     = (_Float16*)alloc(3 * 128 * 128 * 2);
    __half*   xbuf   = (__half*)alloc((size_t)NN * CC * 2);
    __half*   ybuf   = (__half*)alloc((size_t)NN * CC * 2);
    (void)ws_size;

    const int NBn = (NN + 255) / 256;       // 391
    const int NBe = (NE + 255) / 256;       // 6250
    const int NBg = (NN + 63) / 64;         // 1563

    k_init<<<NBn, 256, 0, stream>>>(cnt);
    k_count<<<NBe, 256, 0, stream>>>(ei, cnt, loc);
    k_scan1<<<NB_SCAN, 256, 0, stream>>>(cnt, rowptr, bsum);
    k_scan2<<<1, 512, 0, stream>>>(bsum, boff);
    k_scan3<<<NBn, 256, 0, stream>>>(rowptr, boff);
    k_scatter<<<NBe, 256, 0, stream>>>(ei, ew, loc, rowptr, csr);
    k_degdinv<<<NBn, 256, 0, stream>>>(rowptr, csr, dinv);
    k_mkcsr0<<<NBe, 256, 0, stream>>>(csr, x_idx, dinv, csr0);
    k_wcvt<<<192, 256, 0, stream>>>(conv_w, lin1_w, wt);

    // layer 0: ewh = fp16(emb @ W0); fused gather-aggregate
    k_embw<<<32, 256, 0, stream>>>(emb, conv_w, ewh);
    k_agg0<<<NN / 4, 256, 0, stream>>>(csr0, rowptr, x_idx, dinv, ewh,
                                       conv_b + 0 * CC, (__half2*)xbuf);
    // layer 1
    k_mgemm<0><<<NBg, 256, 0, stream>>>((const _Float16*)xbuf, wt + 0 * 16384, dinv,
                                        nullptr, (_Float16*)ybuf, nullptr, nullptr,
                                        nullptr);
    k_agg<<<NN / 4, 256, 0, stream>>>((const __half2*)ybuf, rowptr, csr, dinv,
                                      conv_b + 1 * CC, (__half2*)xbuf, 1);
    // layer 2
    k_mgemm<0><<<NBg, 256, 0, stream>>>((const _Float16*)xbuf, wt + 1 * 16384, dinv,
                                        nullptr, (_Float16*)ybuf, nullptr, nullptr,
                                        nullptr);
    k_agg<<<NN / 4, 256, 0, stream>>>((const __half2*)ybuf, rowptr, csr, dinv,
                                      conv_b + 2 * CC, (__half2*)xbuf, 0);
    // head: relu(x @ lin1_w + lin1_b) @ lin2_w + lin2_b, fused, MFMA
    k_mgemm<1><<<NBg, 256, 0, stream>>>((const _Float16*)xbuf, wt + 2 * 16384, dinv,
                                        lin1_b, nullptr, lin2_w, lin2_b, out);
}

// Round 6
// 432.875 us; speedup vs baseline: 2.2523x; 1.0271x over previous
//
#include <hip/hip_runtime.h>
#include <hip/hip_fp16.h>

#define NN 100000
#define NE 1600000
#define CC 128
#define NB_SCAN 391            // ceil(NN/256)
#define CAP 1900032            // >= NE + 3*NN, multiple of 256

typedef _Float16 f16x8 __attribute__((ext_vector_type(8)));
typedef float    f32x4 __attribute__((ext_vector_type(4)));

// ---------------- init ----------------
__global__ void k_init(int* cnt) {
    int i = blockIdx.x * 256 + threadIdx.x;
    if (i < NN) cnt[i] = 0;
}

// one atomic per edge; returned value = slot within dst bucket
__global__ void k_count(const int* __restrict__ ei, int* cnt, int* loc) {
    int e = blockIdx.x * 256 + threadIdx.x;
    if (e < NE) {
        int c = ei[NE + e];
        loc[e] = atomicAdd(&cnt[c], 1);
    }
}

// ---------------- prefix scan over PADDED counts (pad rows to mult of 4) ----
__global__ void k_scan1(const int* __restrict__ cnt, int* rowptr, int* bsum) {
    __shared__ int s[256];
    int t = threadIdx.x;
    int i = blockIdx.x * 256 + t;
    int v = (i < NN) ? ((cnt[i] + 3) & ~3) : 0;
    s[t] = v; __syncthreads();
    for (int off = 1; off < 256; off <<= 1) {
        int x = (t >= off) ? s[t - off] : 0;
        __syncthreads();
        s[t] += x;
        __syncthreads();
    }
    if (i < NN) rowptr[i] = s[t] - v;         // exclusive
    if (t == 255) bsum[blockIdx.x] = s[255];  // block total
}

__global__ void k_scan2(const int* __restrict__ bsum, int* boff) {
    __shared__ int s[512];
    int t = threadIdx.x;
    int v = (t < NB_SCAN) ? bsum[t] : 0;
    s[t] = v; __syncthreads();
    for (int off = 1; off < 512; off <<= 1) {
        int x = (t >= off) ? s[t - off] : 0;
        __syncthreads();
        s[t] += x;
        __syncthreads();
    }
    if (t < NB_SCAN) boff[t] = s[t] - v;      // exclusive
}

__global__ void k_scan3(int* rowptr, const int* __restrict__ boff,
                        const int* __restrict__ cnt) {
    int i = blockIdx.x * 256 + threadIdx.x;
    if (i < NN) {
        rowptr[i] += boff[i >> 8];
        if (i == NN - 1) rowptr[NN] = rowptr[i] + ((cnt[i] + 3) & ~3);
    }
}

// atomic-free CSR scatter (csr pre-zeroed; pad slots stay {src=0, w=0})
__global__ void k_scatter(const int* __restrict__ ei, const float* __restrict__ ew,
                          const int* __restrict__ loc, const int* __restrict__ rowptr,
                          int2* __restrict__ csr) {
    int e = blockIdx.x * 256 + threadIdx.x;
    if (e < NE) {
        int c = ei[NE + e];
        int pos = rowptr[c] + loc[e];
        csr[pos] = make_int2(ei[e], __float_as_int(ew[e]));
    }
}

// deg[v] = 1 + sum of row weights (pad w=0 harmless); dinv = rsqrt
__global__ void k_degdinv(const int* __restrict__ rowptr, const int2* __restrict__ csr,
                          float* __restrict__ dinv) {
    int v = blockIdx.x * 256 + threadIdx.x;
    if (v < NN) {
        int b = rowptr[v], e = rowptr[v + 1];
        float s = 1.f;
        for (int i = b; i < e; i++) s += __int_as_float(csr[i].y);
        dinv[v] = rsqrtf(s);
    }
}

// csr0[pos] = {emb_row(src), w*dinv[src]}; over full padded capacity
__global__ void k_mkcsr0(const int2* __restrict__ csr, const int* __restrict__ xidx,
                         const float* __restrict__ dinv, int2* __restrict__ csr0) {
    int e = blockIdx.x * 256 + threadIdx.x;
    if (e < CAP) {
        int2 c = csr[e];
        csr0[e] = make_int2(xidx[c.x],
                            __float_as_int(__int_as_float(c.y) * dinv[c.x]));
    }
}

// Wt[l][j][k] = fp16(W_l[k][j])  (transposed fp16 weights for MFMA B-fragments)
__global__ void k_wcvt(const float* __restrict__ conv_w, const float* __restrict__ lin1_w,
                       _Float16* __restrict__ wt) {
    int t = blockIdx.x * 256 + threadIdx.x;  // 3*16384
    int l = t >> 14, r = t & 16383;
    int j = r >> 7, k = r & 127;
    const float* src = (l < 2) ? (conv_w + (l + 1) * 16384) : lin1_w;
    wt[l * 16384 + j * 128 + k] = (_Float16)src[k * 128 + j];
}

// ---------------- embW0 = emb @ W0, stored fp16 (32KB, L1-resident) ----------
__global__ void k_embw(const float* __restrict__ emb, const float* __restrict__ w0,
                       __half2* __restrict__ ewh) {
    int t = blockIdx.x * 256 + threadIdx.x;  // 8192 threads
    int i = t >> 6, jp = t & 63;
    int j0 = jp * 2;
    float a0 = 0.f, a1 = 0.f;
    for (int k = 0; k < 128; k++) {
        float e = emb[i * 128 + k];
        a0 = fmaf(e, w0[k * 128 + j0], a0);
        a1 = fmaf(e, w0[k * 128 + j0 + 1], a1);
    }
    ewh[t] = __floats2half2_rn(a0, a1);
}

// ---------------- generic quad-edge aggregation core ----------------
// Wave = 4 groups x 16 lanes. Group g handles edge e+g; lane loads 16B of the
// 256B source row. Cross-group reduce via shfl_down(32/16); lanes 0-15 hold
// the full 128-channel sum (8 ch each). Rows are padded to mult-of-4 with
// {idx=0, w=0}, so there is no remainder code.
// MODE_SELF 0: out = relu?(dv*(sum + self) + b)        (self = y[v])
// MODE_SELF 1: out = relu (dv*(sum + dv*ts)   + b)     (ts = table[xidx[v]])
template <int SELF_TABLE, int RELU>
__device__ __forceinline__ void agg_core(const _Float16* __restrict__ src16,
                                         const int2* __restrict__ csr,
                                         const int* __restrict__ rowptr,
                                         const int* __restrict__ xidx,
                                         const float* __restrict__ dinv,
                                         const float* __restrict__ bias,
                                         _Float16* __restrict__ xout) {
    int wave = threadIdx.x >> 6, lane = threadIdx.x & 63;
    int g = lane >> 4, sub = lane & 15;
    int v = blockIdx.x * 4 + wave;
    if (v >= NN) return;
    int beg = rowptr[v], end = rowptr[v + 1];
    float acc[8];
#pragma unroll
    for (int i = 0; i < 8; i++) acc[i] = 0.f;
    int e = beg;
    while (e + 8 <= end) {
        int2 c0 = csr[e + g];
        int2 c1 = csr[e + 4 + g];
        f16x8 t0 = *reinterpret_cast<const f16x8*>(&src16[(size_t)c0.x * 128 + sub * 8]);
        f16x8 t1 = *reinterpret_cast<const f16x8*>(&src16[(size_t)c1.x * 128 + sub * 8]);
        float w0 = __int_as_float(c0.y), w1 = __int_as_float(c1.y);
#pragma unroll
        for (int i = 0; i < 8; i++) acc[i] = fmaf(w0, (float)t0[i], acc[i]);
#pragma unroll
        for (int i = 0; i < 8; i++) acc[i] = fmaf(w1, (float)t1[i], acc[i]);
        e += 8;
    }
    if (e < end) {
        int2 c0 = csr[e + g];
        f16x8 t0 = *reinterpret_cast<const f16x8*>(&src16[(size_t)c0.x * 128 + sub * 8]);
        float w0 = __int_as_float(c0.y);
#pragma unroll
        for (int i = 0; i < 8; i++) acc[i] = fmaf(w0, (float)t0[i], acc[i]);
    }
#pragma unroll
    for (int i = 0; i < 8; i++) {
        acc[i] += __shfl_down(acc[i], 32);
        acc[i] += __shfl_down(acc[i], 16);
    }
    if (g == 0) {
        float dv = dinv[v];
        size_t selfoff = SELF_TABLE ? (size_t)xidx[v] * 128 : (size_t)v * 128;
        f16x8 sf = *reinterpret_cast<const f16x8*>(&src16[selfoff + sub * 8]);
        float4 b0 = reinterpret_cast<const float4*>(bias)[sub * 2];
        float4 b1 = reinterpret_cast<const float4*>(bias)[sub * 2 + 1];
        float bb[8] = {b0.x, b0.y, b0.z, b0.w, b1.x, b1.y, b1.z, b1.w};
        f16x8 o;
#pragma unroll
        for (int i = 0; i < 8; i++) {
            float self = SELF_TABLE ? dv * (float)sf[i] : (float)sf[i];
            float r = fmaf(dv, acc[i] + self, bb[i]);
            if (RELU) r = fmaxf(r, 0.f);
            o[i] = (_Float16)r;
        }
        *reinterpret_cast<f16x8*>(&xout[(size_t)v * 128 + sub * 8]) = o;
    }
}

__global__ void k_agg0(const int2* __restrict__ csr0, const int* __restrict__ rowptr,
                       const int* __restrict__ xidx, const float* __restrict__ dinv,
                       const _Float16* __restrict__ ewh, const float* __restrict__ bias,
                       _Float16* __restrict__ xout) {
    agg_core<1, 1>(ewh, csr0, rowptr, xidx, dinv, bias, xout);
}

__global__ void k_agg_r(const _Float16* __restrict__ y, const int* __restrict__ rowptr,
                        const int2* __restrict__ csr, const float* __restrict__ dinv,
                        const float* __restrict__ bias, _Float16* __restrict__ xout) {
    agg_core<0, 1>(y, csr, rowptr, nullptr, dinv, bias, xout);
}

__global__ void k_agg_n(const _Float16* __restrict__ y, const int* __restrict__ rowptr,
                        const int2* __restrict__ csr, const float* __restrict__ dinv,
                        const float* __restrict__ bias, _Float16* __restrict__ xout) {
    agg_core<0, 0>(y, csr, rowptr, nullptr, dinv, bias, xout);
}

// ---------------- MFMA fp16 GEMM: 64 rows/block, 4 waves, 16 rows/wave -------
// MODE 0: y[n][j] = fp16( dinv[n] * (A@W)[n][j] )
// MODE 1: h = relu(A@W + bias); out[n][0:2] = h @ w2 + b2
template <int MODE>
__global__ __launch_bounds__(256) void k_mgemm(const _Float16* __restrict__ A,
                                               const _Float16* __restrict__ Wt,
                                               const float* __restrict__ dinv,
                                               const float* __restrict__ bias,
                                               _Float16* __restrict__ yout,
                                               const float* __restrict__ w2,
                                               const float* __restrict__ b2,
                                               float* __restrict__ outf) {
    int wid = threadIdx.x >> 6, lane = threadIdx.x & 63;
    int lc = lane & 15, lg = lane >> 4;
    int arow = blockIdx.x * 64 + wid * 16 + lc;   // row this lane loads for A
    bool rok = arow < NN;

    f32x4 acc[8];
#pragma unroll
    for (int j = 0; j < 8; j++) acc[j] = (f32x4){0.f, 0.f, 0.f, 0.f};

#pragma unroll
    for (int kc = 0; kc < 4; kc++) {
        int k0 = kc * 32 + lg * 8;
        f16x8 a = {0, 0, 0, 0, 0, 0, 0, 0};
        if (rok) a = *reinterpret_cast<const f16x8*>(&A[arow * 128 + k0]);
#pragma unroll
        for (int j = 0; j < 8; j++) {
            f16x8 b = *reinterpret_cast<const f16x8*>(&Wt[(j * 16 + lc) * 128 + k0]);
            acc[j] = __builtin_amdgcn_mfma_f32_16x16x32_f16(a, b, acc[j], 0, 0, 0);
        }
    }

    int orow0 = blockIdx.x * 64 + wid * 16 + lg * 4;  // rows for regs r=0..3
    if (MODE == 0) {
        float dv[4];
#pragma unroll
        for (int r = 0; r < 4; r++)
            dv[r] = (orow0 + r < NN) ? dinv[orow0 + r] : 0.f;
#pragma unroll
        for (int j = 0; j < 8; j++) {
#pragma unroll
            for (int r = 0; r < 4; r++) {
                int orow = orow0 + r;
                if (orow < NN)
                    yout[orow * 128 + j * 16 + lc] = (_Float16)(dv[r] * acc[j][r]);
            }
        }
    } else {
        float bj[8], w0j[8], w1j[8];
#pragma unroll
        for (int j = 0; j < 8; j++) {
            int c = j * 16 + lc;
            bj[j] = bias[c];
            w0j[j] = w2[c * 2 + 0];
            w1j[j] = w2[c * 2 + 1];
        }
        float bb0 = b2[0], bb1 = b2[1];
#pragma unroll
        for (int r = 0; r < 4; r++) {
            float p0 = 0.f, p1 = 0.f;
#pragma unroll
            for (int j = 0; j < 8; j++) {
                float h = fmaxf(acc[j][r] + bj[j], 0.f);
                p0 = fmaf(h, w0j[j], p0);
                p1 = fmaf(h, w1j[j], p1);
            }
#pragma unroll
            for (int m = 1; m < 16; m <<= 1) {
                p0 += __shfl_xor(p0, m);
                p1 += __shfl_xor(p1, m);
            }
            int orow = orow0 + r;
            if (lc == 0 && orow < NN)
                *reinterpret_cast<float2*>(&outf[orow * 2]) =
                    make_float2(p0 + bb0, p1 + bb1);
        }
    }
}

extern "C" void kernel_launch(void* const* d_in, const int* in_sizes, int n_in,
                              void* d_out, int out_size, void* d_ws, size_t ws_size,
                              hipStream_t stream) {
    const int*   x_idx  = (const int*)d_in[0];
    const int*   ei     = (const int*)d_in[1];
    const float* ew     = (const float*)d_in[2];
    const float* emb    = (const float*)d_in[3];
    const float* conv_w = (const float*)d_in[4];
    const float* conv_b = (const float*)d_in[5];
    const float* lin1_w = (const float*)d_in[6];
    const float* lin1_b = (const float*)d_in[7];
    const float* lin2_w = (const float*)d_in[8];
    const float* lin2_b = (const float*)d_in[9];
    float* out = (float*)d_out;

    char* ws = (char*)d_ws;
    size_t off = 0;
    auto alloc = [&](size_t bytes) -> void* {
        void* p = ws + off;
        off += (bytes + 255) & ~(size_t)255;
        return p;
    };
    float*    dinv   = (float*)alloc(NN * 4);
    int*      cnt    = (int*)alloc(NN * 4);
    int*      rowptr = (int*)alloc((NN + 1) * 4);
    int*      bsum   = (int*)alloc(512 * 4);
    int*      boff   = (int*)alloc(512 * 4);
    int*      loc    = (int*)alloc((size_t)NE * 4);
    int2*     csr    = (int2*)alloc((size_t)CAP * 8);
    int2*     csr0   = (int2*)alloc((size_t)CAP * 8);
    _Float16* ewh    = (_Float16*)alloc(128 * 128 * 2);
    _Float16* wt     = (_Float16*)alloc(3 * 128 * 128 * 2);
    _Float16* xbuf   = (_Float16*)alloc((size_t)NN * CC * 2);
    _Float16* ybuf   = (_Float16*)alloc((size_t)NN * CC * 2);
    (void)ws_size;

    const int NBn = (NN + 255) / 256;       // 391
    const int NBe = (NE + 255) / 256;       // 6250
    const int NBc = CAP / 256;              // 7422
    const int NBg = (NN + 63) / 64;         // 1563

    hipMemsetAsync(csr, 0, (size_t)CAP * 8, stream);   // pad slots = {src=0, w=0}
    k_init<<<NBn, 256, 0, stream>>>(cnt);
    k_count<<<NBe, 256, 0, stream>>>(ei, cnt, loc);
    k_scan1<<<NB_SCAN, 256, 0, stream>>>(cnt, rowptr, bsum);
    k_scan2<<<1, 512, 0, stream>>>(bsum, boff);
    k_scan3<<<NBn, 256, 0, stream>>>(rowptr, boff, cnt);
    k_scatter<<<NBe, 256, 0, stream>>>(ei, ew, loc, rowptr, csr);
    k_degdinv<<<NBn, 256, 0, stream>>>(rowptr, csr, dinv);
    k_mkcsr0<<<NBc, 256, 0, stream>>>(csr, x_idx, dinv, csr0);
    k_wcvt<<<192, 256, 0, stream>>>(conv_w, lin1_w, wt);

    // layer 0: ewh = fp16(emb @ W0); fused gather-aggregate from L1 table
    k_embw<<<32, 256, 0, stream>>>(emb, conv_w, (__half2*)ewh);
    k_agg0<<<NN / 4, 256, 0, stream>>>(csr0, rowptr, x_idx, dinv, ewh,
                                       conv_b + 0 * CC, xbuf);
    // layer 1
    k_mgemm<0><<<NBg, 256, 0, stream>>>(xbuf, wt + 0 * 16384, dinv, nullptr, ybuf,
                                        nullptr, nullptr, nullptr);
    k_agg_r<<<NN / 4, 256, 0, stream>>>(ybuf, rowptr, csr, dinv, conv_b + 1 * CC, xbuf);
    // layer 2
    k_mgemm<0><<<NBg, 256, 0, stream>>>(xbuf, wt + 1 * 16384, dinv, nullptr, ybuf,
                                        nullptr, nullptr, nullptr);
    k_agg_n<<<NN / 4, 256, 0, stream>>>(ybuf, rowptr, csr, dinv, conv_b + 2 * CC, xbuf);
    // head: relu(x @ lin1_w + lin1_b) @ lin2_w + lin2_b, fused, MFMA
    k_mgemm<1><<<NBg, 256, 0, stream>>>(xbuf, wt + 2 * 16384, dinv, lin1_b, nullptr,
                                        lin2_w, lin2_b, out);
}

// Round 7
// 390.656 us; speedup vs baseline: 2.4957x; 1.1081x over previous
//
#include <hip/hip_runtime.h>
#include <hip/hip_fp16.h>

#define NN 100000
#define NE 1600000
#define CC 128
#define NBIN 782      // ceil(NN/128) coarse bins (128 nodes each)
#define BPW 128       // nodes per bin
#define MAXB 2560     // bucket capacity (mean 2048, sigma ~45 -> 11 sigma)
#define NHB 256       // histogram blocks
#define EPB 6250      // edges per histogram block (NE/NHB exact)

typedef _Float16 f16x8 __attribute__((ext_vector_type(8)));
typedef float    f32x4 __attribute__((ext_vector_type(4)));

// ---------------- pass 1: per-block coarse histograms (no global atomics) ----
__global__ __launch_bounds__(256) void k_hist(const int* __restrict__ ei,
                                              int* __restrict__ hist) {
    __shared__ int h[NBIN];
    for (int i = threadIdx.x; i < NBIN; i += 256) h[i] = 0;
    __syncthreads();
    int base = blockIdx.x * EPB;
    for (int i = threadIdx.x; i < EPB; i += 256) {
        int d = ei[NE + base + i];
        atomicAdd(&h[d >> 7], 1);
    }
    __syncthreads();
    for (int i = threadIdx.x; i < NBIN; i += 256)
        hist[blockIdx.x * NBIN + i] = h[i];
}

// ---------------- scan A: per bin, scan counts across the 256 blocks --------
__global__ __launch_bounds__(256) void k_scanA(const int* __restrict__ hist,
                                               int* __restrict__ blockBase,
                                               int* __restrict__ binTotal) {
    __shared__ int s[256];
    int bin = blockIdx.x, t = threadIdx.x;
    int v = hist[t * NBIN + bin];
    s[t] = v; __syncthreads();
    for (int off = 1; off < 256; off <<= 1) {
        int x = (t >= off) ? s[t - off] : 0;
        __syncthreads();
        s[t] += x;
        __syncthreads();
    }
    blockBase[t * NBIN + bin] = s[t] - v;   // exclusive within bin
    if (t == 255) binTotal[bin] = s[255];
}

// ---------------- scan B: exclusive scan over bin totals ----------------
__global__ __launch_bounds__(1024) void k_scanB(const int* __restrict__ binTotal,
                                                int* __restrict__ binStart) {
    __shared__ int s[1024];
    int t = threadIdx.x;
    int v = (t < NBIN) ? binTotal[t] : 0;
    s[t] = v; __syncthreads();
    for (int off = 1; off < 1024; off <<= 1) {
        int x = (t >= off) ? s[t - off] : 0;
        __syncthreads();
        s[t] += x;
        __syncthreads();
    }
    if (t < NBIN) binStart[t] = s[t] - v;
    if (t == 1023) binStart[NBIN] = s[1023];   // == NE
}

// ---------------- pass 2: scatter edges into coarse buckets (LDS ranks) -----
__global__ __launch_bounds__(256) void k_pass2(const int* __restrict__ ei,
                                               const float* __restrict__ ew,
                                               const int* __restrict__ binStart,
                                               const int* __restrict__ blockBase,
                                               int2* __restrict__ pay,
                                               unsigned char* __restrict__ key) {
    __shared__ int cur[NBIN];
    int blk = blockIdx.x;
    for (int i = threadIdx.x; i < NBIN; i += 256)
        cur[i] = binStart[i] + blockBase[blk * NBIN + i];
    __syncthreads();
    int base = blk * EPB;
    for (int i = threadIdx.x; i < EPB; i += 256) {
        int e = base + i;
        int d = ei[NE + e];
        int src = ei[e];
        float w = ew[e];
        int pos = atomicAdd(&cur[d >> 7], 1);
        pay[pos] = make_int2(src, __float_as_int(w));
        key[pos] = (unsigned char)(d & 127);
    }
}

// ---------------- pass 3: per-bucket local sort -> CSR + rowptr + dinv ------
__global__ __launch_bounds__(256) void k_pass3(const int* __restrict__ binStart,
                                               const int2* __restrict__ pay,
                                               const unsigned char* __restrict__ key,
                                               int2* __restrict__ csr,
                                               int* __restrict__ rowptr,
                                               float* __restrict__ dinv) {
    __shared__ int2 sp[MAXB];
    __shared__ unsigned char sk[MAXB];
    __shared__ int hist[BPW], excl[BPW], cur[BPW];
    __shared__ float degw[BPW];
    int b = blockIdx.x, t = threadIdx.x;
    int s0 = binStart[b], s1 = binStart[b + 1];
    int n = s1 - s0;
    if (t < BPW) { hist[t] = 0; degw[t] = 0.f; }
    __syncthreads();
    for (int i = t; i < n; i += 256) {
        int2 p = pay[s0 + i];
        unsigned char k = key[s0 + i];
        sp[i] = p; sk[i] = k;
        atomicAdd(&hist[k], 1);
    }
    __syncthreads();
    if (t < BPW) excl[t] = hist[t];
    __syncthreads();
    for (int off = 1; off < BPW; off <<= 1) {
        int x = (t < BPW && t >= off) ? excl[t - off] : 0;
        __syncthreads();
        if (t < BPW) excl[t] += x;
        __syncthreads();
    }
    if (t < BPW) {
        int ex = excl[t] - hist[t];
        excl[t] = ex;
        cur[t] = ex;
    }
    __syncthreads();
    int node0 = b * BPW;
    if (t < BPW && node0 + t < NN) rowptr[node0 + t] = s0 + excl[t];
    if (b == NBIN - 1 && t == 0) rowptr[NN] = NE;
    for (int i = t; i < n; i += 256) {
        int2 p = sp[i];
        unsigned char k = sk[i];
        int pos = atomicAdd(&cur[k], 1);
        csr[s0 + pos] = p;
        atomicAdd(&degw[k], __int_as_float(p.y));
    }
    __syncthreads();
    if (t < BPW && node0 + t < NN) dinv[node0 + t] = rsqrtf(1.f + degw[t]);
}

// csr0[pos] = {emb_row(src), w*dinv[src]}
__global__ void k_mkcsr0(const int2* __restrict__ csr, const int* __restrict__ xidx,
                         const float* __restrict__ dinv, int2* __restrict__ csr0) {
    int e = blockIdx.x * 256 + threadIdx.x;
    if (e < NE) {
        int2 c = csr[e];
        csr0[e] = make_int2(xidx[c.x],
                            __float_as_int(__int_as_float(c.y) * dinv[c.x]));
    }
}

// Wt[l][j][k] = fp16(W_l[k][j])  (transposed fp16 weights for MFMA B-fragments)
__global__ void k_wcvt(const float* __restrict__ conv_w, const float* __restrict__ lin1_w,
                       _Float16* __restrict__ wt) {
    int t = blockIdx.x * 256 + threadIdx.x;  // 3*16384
    int l = t >> 14, r = t & 16383;
    int j = r >> 7, k = r & 127;
    const float* src = (l < 2) ? (conv_w + (l + 1) * 16384) : lin1_w;
    wt[l * 16384 + j * 128 + k] = (_Float16)src[k * 128 + j];
}

// ---------------- embW0 = emb @ W0, stored fp16 (32KB, L1-resident) ----------
__global__ void k_embw(const float* __restrict__ emb, const float* __restrict__ w0,
                       __half2* __restrict__ ewh) {
    int t = blockIdx.x * 256 + threadIdx.x;  // 8192 threads
    int i = t >> 6, jp = t & 63;
    int j0 = jp * 2;
    float a0 = 0.f, a1 = 0.f;
    for (int k = 0; k < 128; k++) {
        float e = emb[i * 128 + k];
        a0 = fmaf(e, w0[k * 128 + j0], a0);
        a1 = fmaf(e, w0[k * 128 + j0 + 1], a1);
    }
    ewh[t] = __floats2half2_rn(a0, a1);
}

// ---------------- generic quad-edge aggregation core ----------------
// Wave = 4 groups x 16 lanes. Group g handles edge e+g; lane loads 16B of the
// 256B source row. Cross-group reduce via shfl_down(32/16). Unpadded rows:
// main loop 8-wide unguarded, tail 4-wide with w=0 clamp.
template <int SELF_TABLE, int RELU>
__device__ __forceinline__ void agg_core(const _Float16* __restrict__ src16,
                                         const int2* __restrict__ csr,
                                         const int* __restrict__ rowptr,
                                         const int* __restrict__ xidx,
                                         const float* __restrict__ dinv,
                                         const float* __restrict__ bias,
                                         _Float16* __restrict__ xout) {
    int wave = threadIdx.x >> 6, lane = threadIdx.x & 63;
    int g = lane >> 4, sub = lane & 15;
    int v = blockIdx.x * 4 + wave;
    if (v >= NN) return;
    int beg = rowptr[v], end = rowptr[v + 1];
    float acc[8];
#pragma unroll
    for (int i = 0; i < 8; i++) acc[i] = 0.f;
    int e = beg;
    while (e + 8 <= end) {
        int2 c0 = csr[e + g];
        int2 c1 = csr[e + 4 + g];
        f16x8 t0 = *reinterpret_cast<const f16x8*>(&src16[(size_t)c0.x * 128 + sub * 8]);
        f16x8 t1 = *reinterpret_cast<const f16x8*>(&src16[(size_t)c1.x * 128 + sub * 8]);
        float w0 = __int_as_float(c0.y), w1 = __int_as_float(c1.y);
#pragma unroll
        for (int i = 0; i < 8; i++) acc[i] = fmaf(w0, (float)t0[i], acc[i]);
#pragma unroll
        for (int i = 0; i < 8; i++) acc[i] = fmaf(w1, (float)t1[i], acc[i]);
        e += 8;
    }
    for (; e < end; e += 4) {
        int idx = e + g;
        bool ok = idx < end;
        int2 c0 = csr[ok ? idx : beg];
        float w0 = ok ? __int_as_float(c0.y) : 0.f;
        f16x8 t0 = *reinterpret_cast<const f16x8*>(&src16[(size_t)c0.x * 128 + sub * 8]);
#pragma unroll
        for (int i = 0; i < 8; i++) acc[i] = fmaf(w0, (float)t0[i], acc[i]);
    }
#pragma unroll
    for (int i = 0; i < 8; i++) {
        acc[i] += __shfl_down(acc[i], 32);
        acc[i] += __shfl_down(acc[i], 16);
    }
    if (g == 0) {
        float dv = dinv[v];
        size_t selfoff = SELF_TABLE ? (size_t)xidx[v] * 128 : (size_t)v * 128;
        f16x8 sf = *reinterpret_cast<const f16x8*>(&src16[selfoff + sub * 8]);
        float4 b0 = reinterpret_cast<const float4*>(bias)[sub * 2];
        float4 b1 = reinterpret_cast<const float4*>(bias)[sub * 2 + 1];
        float bb[8] = {b0.x, b0.y, b0.z, b0.w, b1.x, b1.y, b1.z, b1.w};
        f16x8 o;
#pragma unroll
        for (int i = 0; i < 8; i++) {
            float self = SELF_TABLE ? dv * (float)sf[i] : (float)sf[i];
            float r = fmaf(dv, acc[i] + self, bb[i]);
            if (RELU) r = fmaxf(r, 0.f);
            o[i] = (_Float16)r;
        }
        *reinterpret_cast<f16x8*>(&xout[(size_t)v * 128 + sub * 8]) = o;
    }
}

__global__ void k_agg0(const int2* __restrict__ csr0, const int* __restrict__ rowptr,
                       const int* __restrict__ xidx, const float* __restrict__ dinv,
                       const _Float16* __restrict__ ewh, const float* __restrict__ bias,
                       _Float16* __restrict__ xout) {
    agg_core<1, 1>(ewh, csr0, rowptr, xidx, dinv, bias, xout);
}

__global__ void k_agg_r(const _Float16* __restrict__ y, const int* __restrict__ rowptr,
                        const int2* __restrict__ csr, const float* __restrict__ dinv,
                        const float* __restrict__ bias, _Float16* __restrict__ xout) {
    agg_core<0, 1>(y, csr, rowptr, nullptr, dinv, bias, xout);
}

__global__ void k_agg_n(const _Float16* __restrict__ y, const int* __restrict__ rowptr,
                        const int2* __restrict__ csr, const float* __restrict__ dinv,
                        const float* __restrict__ bias, _Float16* __restrict__ xout) {
    agg_core<0, 0>(y, csr, rowptr, nullptr, dinv, bias, xout);
}

// ---------------- MFMA fp16 GEMM: 64 rows/block, 4 waves, 16 rows/wave -------
// MODE 0: y[n][j] = fp16( dinv[n] * (A@W)[n][j] )
// MODE 1: h = relu(A@W + bias); out[n][0:2] = h @ w2 + b2
template <int MODE>
__global__ __launch_bounds__(256) void k_mgemm(const _Float16* __restrict__ A,
                                               const _Float16* __restrict__ Wt,
                                               const float* __restrict__ dinv,
                                               const float* __restrict__ bias,
                                               _Float16* __restrict__ yout,
                                               const float* __restrict__ w2,
                                               const float* __restrict__ b2,
                                               float* __restrict__ outf) {
    int wid = threadIdx.x >> 6, lane = threadIdx.x & 63;
    int lc = lane & 15, lg = lane >> 4;
    int arow = blockIdx.x * 64 + wid * 16 + lc;   // row this lane loads for A
    bool rok = arow < NN;

    f32x4 acc[8];
#pragma unroll
    for (int j = 0; j < 8; j++) acc[j] = (f32x4){0.f, 0.f, 0.f, 0.f};

#pragma unroll
    for (int kc = 0; kc < 4; kc++) {
        int k0 = kc * 32 + lg * 8;
        f16x8 a = {0, 0, 0, 0, 0, 0, 0, 0};
        if (rok) a = *reinterpret_cast<const f16x8*>(&A[arow * 128 + k0]);
#pragma unroll
        for (int j = 0; j < 8; j++) {
            f16x8 b = *reinterpret_cast<const f16x8*>(&Wt[(j * 16 + lc) * 128 + k0]);
            acc[j] = __builtin_amdgcn_mfma_f32_16x16x32_f16(a, b, acc[j], 0, 0, 0);
        }
    }

    int orow0 = blockIdx.x * 64 + wid * 16 + lg * 4;  // rows for regs r=0..3
    if (MODE == 0) {
        float dv[4];
#pragma unroll
        for (int r = 0; r < 4; r++)
            dv[r] = (orow0 + r < NN) ? dinv[orow0 + r] : 0.f;
#pragma unroll
        for (int j = 0; j < 8; j++) {
#pragma unroll
            for (int r = 0; r < 4; r++) {
                int orow = orow0 + r;
                if (orow < NN)
                    yout[orow * 128 + j * 16 + lc] = (_Float16)(dv[r] * acc[j][r]);
            }
        }
    } else {
        float bj[8], w0j[8], w1j[8];
#pragma unroll
        for (int j = 0; j < 8; j++) {
            int c = j * 16 + lc;
            bj[j] = bias[c];
            w0j[j] = w2[c * 2 + 0];
            w1j[j] = w2[c * 2 + 1];
        }
        float bb0 = b2[0], bb1 = b2[1];
#pragma unroll
        for (int r = 0; r < 4; r++) {
            float p0 = 0.f, p1 = 0.f;
#pragma unroll
            for (int j = 0; j < 8; j++) {
                float h = fmaxf(acc[j][r] + bj[j], 0.f);
                p0 = fmaf(h, w0j[j], p0);
                p1 = fmaf(h, w1j[j], p1);
            }
#pragma unroll
            for (int m = 1; m < 16; m <<= 1) {
                p0 += __shfl_xor(p0, m);
                p1 += __shfl_xor(p1, m);
            }
            int orow = orow0 + r;
            if (lc == 0 && orow < NN)
                *reinterpret_cast<float2*>(&outf[orow * 2]) =
                    make_float2(p0 + bb0, p1 + bb1);
        }
    }
}

extern "C" void kernel_launch(void* const* d_in, const int* in_sizes, int n_in,
                              void* d_out, int out_size, void* d_ws, size_t ws_size,
                              hipStream_t stream) {
    const int*   x_idx  = (const int*)d_in[0];
    const int*   ei     = (const int*)d_in[1];
    const float* ew     = (const float*)d_in[2];
    const float* emb    = (const float*)d_in[3];
    const float* conv_w = (const float*)d_in[4];
    const float* conv_b = (const float*)d_in[5];
    const float* lin1_w = (const float*)d_in[6];
    const float* lin1_b = (const float*)d_in[7];
    const float* lin2_w = (const float*)d_in[8];
    const float* lin2_b = (const float*)d_in[9];
    float* out = (float*)d_out;

    char* ws = (char*)d_ws;
    size_t off = 0;
    auto alloc = [&](size_t bytes) -> void* {
        void* p = ws + off;
        off += (bytes + 255) & ~(size_t)255;
        return p;
    };
    float*         dinv      = (float*)alloc(NN * 4);
    int*           rowptr    = (int*)alloc((NN + 1) * 4);
    int*           hist      = (int*)alloc((size_t)NHB * NBIN * 4);
    int*           blockBase = (int*)alloc((size_t)NHB * NBIN * 4);
    int*           binTotal  = (int*)alloc(NBIN * 4);
    int*           binStart  = (int*)alloc((NBIN + 1) * 4);
    int2*          pay       = (int2*)alloc((size_t)NE * 8);
    unsigned char* key       = (unsigned char*)alloc(NE);
    int2*          csr       = (int2*)alloc((size_t)NE * 8);
    int2*          csr0      = (int2*)alloc((size_t)NE * 8);
    _Float16*      ewh       = (_Float16*)alloc(128 * 128 * 2);
    _Float16*      wt        = (_Float16*)alloc(3 * 128 * 128 * 2);
    _Float16*      xbuf      = (_Float16*)alloc((size_t)NN * CC * 2);
    _Float16*      ybuf      = (_Float16*)alloc((size_t)NN * CC * 2);
    (void)ws_size;

    const int NBe = (NE + 255) / 256;       // 6250
    const int NBg = (NN + 63) / 64;         // 1563

    // CSR build: 2-level counting sort, no global atomics
    k_hist<<<NHB, 256, 0, stream>>>(ei, hist);
    k_scanA<<<NBIN, 256, 0, stream>>>(hist, blockBase, binTotal);
    k_scanB<<<1, 1024, 0, stream>>>(binTotal, binStart);
    k_pass2<<<NHB, 256, 0, stream>>>(ei, ew, binStart, blockBase, pay, key);
    k_pass3<<<NBIN, 256, 0, stream>>>(binStart, pay, key, csr, rowptr, dinv);
    k_mkcsr0<<<NBe, 256, 0, stream>>>(csr, x_idx, dinv, csr0);
    k_wcvt<<<192, 256, 0, stream>>>(conv_w, lin1_w, wt);

    // layer 0: ewh = fp16(emb @ W0); fused gather-aggregate from L1 table
    k_embw<<<32, 256, 0, stream>>>(emb, conv_w, (__half2*)ewh);
    k_agg0<<<NN / 4, 256, 0, stream>>>(csr0, rowptr, x_idx, dinv, ewh,
                                       conv_b + 0 * CC, xbuf);
    // layer 1
    k_mgemm<0><<<NBg, 256, 0, stream>>>(xbuf, wt + 0 * 16384, dinv, nullptr, ybuf,
                                        nullptr, nullptr, nullptr);
    k_agg_r<<<NN / 4, 256, 0, stream>>>(ybuf, rowptr, csr, dinv, conv_b + 1 * CC, xbuf);
    // layer 2
    k_mgemm<0><<<NBg, 256, 0, stream>>>(xbuf, wt + 1 * 16384, dinv, nullptr, ybuf,
                                        nullptr, nullptr, nullptr);
    k_agg_n<<<NN / 4, 256, 0, stream>>>(ybuf, rowptr, csr, dinv, conv_b + 2 * CC, xbuf);
    // head: relu(x @ lin1_w + lin1_b) @ lin2_w + lin2_b, fused, MFMA
    k_mgemm<1><<<NBg, 256, 0, stream>>>(xbuf, wt + 2 * 16384, dinv, lin1_b, nullptr,
                                        lin2_w, lin2_b, out);
}